// Round 1
// baseline (1044.004 us; speedup 1.0000x reference)
//
#include <hip/hip_runtime.h>
#include <math.h>

#define Bv   16
#define Nv   256
#define Dv   512
#define Hv   8
#define DKv  64
#define QT   4

// ---------------------------------------------------------------------------
// Generic C[4096,512] = A[4096,512] @ W[512,512] + bias   (fp32, 64x64 tile)
// ---------------------------------------------------------------------------
__global__ __launch_bounds__(256) void gemm_bias_kernel(
    const float* __restrict__ A, const float* __restrict__ W,
    const float* __restrict__ bias, float* __restrict__ C)
{
    __shared__ float As[16][64];   // transposed A tile: As[k][m]
    __shared__ float Bs[16][64];   // Bs[k][n]
    const int t  = threadIdx.x;
    const int m0 = blockIdx.y * 64;
    const int n0 = blockIdx.x * 64;
    const int tm = (t >> 4) * 4;
    const int tn = (t & 15) * 4;
    const int ar = t >> 2;          // 0..63
    const int ac = (t & 3) * 4;     // 0,4,8,12
    const int br = t >> 4;          // 0..15
    const int bc = (t & 15) * 4;    // 0..60

    const float* Aptr = A + (m0 + ar) * Dv + ac;
    const float* Wptr = W + br * Dv + n0 + bc;

    float acc[4][4] = {};

    for (int k0 = 0; k0 < Dv; k0 += 16) {
        float4 a4 = *(const float4*)(Aptr + k0);
        float4 b4 = *(const float4*)(Wptr + k0 * Dv);
        __syncthreads();   // protect previous iteration's reads
        As[ac + 0][ar] = a4.x;
        As[ac + 1][ar] = a4.y;
        As[ac + 2][ar] = a4.z;
        As[ac + 3][ar] = a4.w;
        *(float4*)(&Bs[br][bc]) = b4;
        __syncthreads();
#pragma unroll
        for (int kk = 0; kk < 16; ++kk) {
            const float a0 = As[kk][tm + 0];
            const float a1 = As[kk][tm + 1];
            const float a2 = As[kk][tm + 2];
            const float a3 = As[kk][tm + 3];
            const float b0 = Bs[kk][tn + 0];
            const float b1 = Bs[kk][tn + 1];
            const float b2 = Bs[kk][tn + 2];
            const float b3 = Bs[kk][tn + 3];
            acc[0][0] += a0 * b0; acc[0][1] += a0 * b1; acc[0][2] += a0 * b2; acc[0][3] += a0 * b3;
            acc[1][0] += a1 * b0; acc[1][1] += a1 * b1; acc[1][2] += a1 * b2; acc[1][3] += a1 * b3;
            acc[2][0] += a2 * b0; acc[2][1] += a2 * b1; acc[2][2] += a2 * b2; acc[2][3] += a2 * b3;
            acc[3][0] += a3 * b0; acc[3][1] += a3 * b1; acc[3][2] += a3 * b2; acc[3][3] += a3 * b3;
        }
    }

    const float4 bia = *(const float4*)(bias + n0 + tn);
#pragma unroll
    for (int i = 0; i < 4; ++i) {
        float4 o;
        o.x = acc[i][0] + bia.x;
        o.y = acc[i][1] + bia.y;
        o.z = acc[i][2] + bia.z;
        o.w = acc[i][3] + bia.w;
        *(float4*)(C + (m0 + tm + i) * Dv + n0 + tn) = o;
    }
}

// ---------------------------------------------------------------------------
// Fused attention: geo bias (sin/cos computed once per (b,q,m) for all heads)
// + QK^T/8 + mask + softmax + PV.  Block = (b, q-tile of 4), 256 threads,
// thread t owns key m = t.  Q/K/V token-major [B,N,512]; head h = cols h*64..
// ---------------------------------------------------------------------------
__global__ __launch_bounds__(256) void attn_kernel(
    const float* __restrict__ Q2, const float* __restrict__ K2,
    const float* __restrict__ V2, const float* __restrict__ box,
    const int* __restrict__ mask, const float* __restrict__ WGw,
    const float* __restrict__ WGb, float* __restrict__ CTX)
{
    const int b  = blockIdx.x >> 6;          // N/QT = 64 tiles per batch
    const int q0 = (blockIdx.x & 63) * QT;
    const int t  = threadIdx.x;              // key index m
    const int lane = t & 63;
    const int wave = t >> 6;

    __shared__ float Qs[QT][Dv];             // 8 KB
    __shared__ float Bsh[QT][Hv][Nv];        // 32 KB  log-geo-bias
    __shared__ float Ps[QT][Nv];             // 4 KB   probabilities
    __shared__ float Wg[Hv * 64];            // 2 KB
    __shared__ float Wgb[Hv];
    __shared__ float qgeo[QT][4];            // cx, cy, w, h of queries
    __shared__ float red[2][QT][4];          // cross-wave reduction scratch

    // --- stage weights / Q tile / query geometry ---
    if (t < Hv) Wgb[t] = WGb[t];
    Wg[t]       = WGw[t];
    Wg[t + 256] = WGw[t + 256];
    {
        const float4* src = (const float4*)(Q2 + (b * Nv + q0) * Dv);
        float4* dst = (float4*)(&Qs[0][0]);
        dst[t]       = src[t];
        dst[t + 256] = src[t + 256];
    }
    if (t < QT) {
        float4 bx = *(const float4*)(box + (b * Nv + q0 + t) * 4);
        qgeo[t][0] = (bx.x + bx.z) * 0.5f;   // cx
        qgeo[t][1] = (bx.y + bx.w) * 0.5f;   // cy
        qgeo[t][2] = bx.z - bx.x + 1.0f;     // w
        qgeo[t][3] = bx.w - bx.y + 1.0f;     // h
    }
    // this thread's key-box geometry
    const float4 bm = *(const float4*)(box + (b * Nv + t) * 4);
    const float cxm = (bm.x + bm.z) * 0.5f;
    const float cym = (bm.y + bm.w) * 0.5f;
    const float wm  = bm.z - bm.x + 1.0f;
    const float hm  = bm.w - bm.y + 1.0f;
    const int   msk = mask[b * Nv + t];
    __syncthreads();

    // --- geometric bias for all heads, all QT queries, this key ---
    const float dimm[8] = {1.0f, 0.42169650342f, 0.17782794100f, 0.07498942093f,
                           0.03162277660f, 0.01333521432f, 0.00562341325f, 0.00237137371f};
    for (int q = 0; q < QT; ++q) {
        const float cxq = qgeo[q][0], cyq = qgeo[q][1];
        const float wq  = qgeo[q][2], hq  = qgeo[q][3];
        float delta[4];
        delta[0] = __logf(fmaxf(fabsf((cxq - cxm) / wq), 1e-3f));
        delta[1] = __logf(fmaxf(fabsf((cyq - cym) / hq), 1e-3f));
        delta[2] = __logf(wq / wm);
        delta[3] = __logf(hq / hm);
        float wg[Hv];
#pragma unroll
        for (int h = 0; h < Hv; ++h) wg[h] = Wgb[h];
        for (int d = 0; d < 4; ++d) {
            const float base = 100.0f * delta[d];
#pragma unroll
            for (int j = 0; j < 8; ++j) {
                const float ang = base * dimm[j];
                const float s = sinf(ang);
                const float c = cosf(ang);
                const int idx = d * 8 + j;
#pragma unroll
                for (int h = 0; h < Hv; ++h)
                    wg[h] += s * Wg[h * 64 + idx] + c * Wg[h * 64 + 32 + idx];
            }
        }
#pragma unroll
        for (int h = 0; h < Hv; ++h)
            Bsh[q][h][t] = __logf(fmaxf(wg[h], 1e-6f));
    }
    __syncthreads();

    // --- per-head: scores -> softmax -> PV ---
    const float* Kb = K2 + (b * Nv + t) * Dv;
    for (int h = 0; h < Hv; ++h) {
        const int cbase = h * DKv;
        float acc[QT] = {0.f, 0.f, 0.f, 0.f};
        for (int c = 0; c < DKv; c += 4) {
            const float4 k4 = *(const float4*)(Kb + cbase + c);
#pragma unroll
            for (int q = 0; q < QT; ++q) {
                const float4 q4 = *(const float4*)(&Qs[q][cbase + c]);
                acc[q] += k4.x * q4.x + k4.y * q4.y + k4.z * q4.z + k4.w * q4.w;
            }
        }
        float sc[QT], p[QT];
#pragma unroll
        for (int q = 0; q < QT; ++q)
            sc[q] = acc[q] * 0.125f + Bsh[q][h][t] + (msk == 0 ? -1e9f : 0.0f);

        // block-wide softmax per query row (wave shuffle + LDS combine)
#pragma unroll
        for (int q = 0; q < QT; ++q) {
            float v = sc[q];
#pragma unroll
            for (int off = 32; off > 0; off >>= 1) v = fmaxf(v, __shfl_xor(v, off, 64));
            if (lane == 0) red[0][q][wave] = v;
        }
        __syncthreads();
#pragma unroll
        for (int q = 0; q < QT; ++q) {
            const float gm = fmaxf(fmaxf(red[0][q][0], red[0][q][1]),
                                   fmaxf(red[0][q][2], red[0][q][3]));
            p[q] = __expf(sc[q] - gm);
            float v = p[q];
#pragma unroll
            for (int off = 32; off > 0; off >>= 1) v += __shfl_xor(v, off, 64);
            if (lane == 0) red[1][q][wave] = v;
        }
        __syncthreads();
#pragma unroll
        for (int q = 0; q < QT; ++q) {
            const float tot = red[1][q][0] + red[1][q][1] + red[1][q][2] + red[1][q][3];
            Ps[q][t] = p[q] / tot;
        }
        __syncthreads();

        // PV: thread -> (query group, dim)
        const int d  = t & 63;
        const int qg = t >> 6;
        const float* Vb = V2 + b * (Nv * Dv) + cbase + d;
        float o = 0.f;
#pragma unroll 4
        for (int m = 0; m < Nv; ++m) o += Ps[qg][m] * Vb[m * Dv];
        CTX[(b * Nv + q0 + qg) * Dv + cbase + d] = o;
        __syncthreads();   // before next head overwrites Ps/red
    }
}

// ---------------------------------------------------------------------------
extern "C" void kernel_launch(void* const* d_in, const int* in_sizes, int n_in,
                              void* d_out, int out_size, void* d_ws, size_t ws_size,
                              hipStream_t stream) {
    (void)in_sizes; (void)n_in; (void)out_size; (void)ws_size;

    const float* inq  = (const float*)d_in[0];
    const float* ink  = (const float*)d_in[1];
    const float* inv  = (const float*)d_in[2];
    const float* box  = (const float*)d_in[3];
    const int*   mask = (const int*)d_in[4];
    const float* Wq   = (const float*)d_in[5];
    const float* bq   = (const float*)d_in[6];
    const float* Wk   = (const float*)d_in[7];
    const float* bk   = (const float*)d_in[8];
    const float* Wv   = (const float*)d_in[9];
    const float* bv   = (const float*)d_in[10];
    const float* Wo   = (const float*)d_in[11];
    const float* bo   = (const float*)d_in[12];
    const float* WGw  = (const float*)d_in[13];
    const float* WGb  = (const float*)d_in[14];

    float* ws  = (float*)d_ws;
    float* Q2  = ws;                 // [B,N,512]
    float* K2  = ws + 2097152;
    float* V2  = ws + 4194304;
    float* CTX = ws + 6291456;       // 32 MB total ws use
    float* out = (float*)d_out;

    dim3 ggrid(Dv / 64, (Bv * Nv) / 64);   // (8, 64)
    gemm_bias_kernel<<<ggrid, 256, 0, stream>>>(inq, Wq, bq, Q2);
    gemm_bias_kernel<<<ggrid, 256, 0, stream>>>(ink, Wk, bk, K2);
    gemm_bias_kernel<<<ggrid, 256, 0, stream>>>(inv, Wv, bv, V2);

    attn_kernel<<<Bv * (Nv / QT), 256, 0, stream>>>(Q2, K2, V2, box, mask, WGw, WGb, CTX);

    gemm_bias_kernel<<<ggrid, 256, 0, stream>>>(CTX, Wo, bo, out);
}

// Round 2
// 375.614 us; speedup vs baseline: 2.7795x; 2.7795x over previous
//
#include <hip/hip_runtime.h>
#include <math.h>

#define Bv   16
#define Nv   256
#define Dv   512
#define Hv   8
#define DKv  64
#define QT   4

// ---------------------------------------------------------------------------
// Generic C[4096,512] = A[4096,512] @ W[512,512] + bias   (fp32, 64x64 tile)
// ---------------------------------------------------------------------------
__global__ __launch_bounds__(256) void gemm_bias_kernel(
    const float* __restrict__ A, const float* __restrict__ W,
    const float* __restrict__ bias, float* __restrict__ C)
{
    __shared__ float As[16][64];   // transposed A tile: As[k][m]
    __shared__ float Bs[16][64];   // Bs[k][n]
    const int t  = threadIdx.x;
    const int m0 = blockIdx.y * 64;
    const int n0 = blockIdx.x * 64;
    const int tm = (t >> 4) * 4;
    const int tn = (t & 15) * 4;
    const int ar = t >> 2;          // 0..63
    const int ac = (t & 3) * 4;     // 0,4,8,12
    const int br = t >> 4;          // 0..15
    const int bc = (t & 15) * 4;    // 0..60

    const float* Aptr = A + (m0 + ar) * Dv + ac;
    const float* Wptr = W + br * Dv + n0 + bc;

    float acc[4][4] = {};

    for (int k0 = 0; k0 < Dv; k0 += 16) {
        float4 a4 = *(const float4*)(Aptr + k0);
        float4 b4 = *(const float4*)(Wptr + k0 * Dv);
        __syncthreads();   // protect previous iteration's reads
        As[ac + 0][ar] = a4.x;
        As[ac + 1][ar] = a4.y;
        As[ac + 2][ar] = a4.z;
        As[ac + 3][ar] = a4.w;
        *(float4*)(&Bs[br][bc]) = b4;
        __syncthreads();
#pragma unroll
        for (int kk = 0; kk < 16; ++kk) {
            const float a0 = As[kk][tm + 0];
            const float a1 = As[kk][tm + 1];
            const float a2 = As[kk][tm + 2];
            const float a3 = As[kk][tm + 3];
            const float b0 = Bs[kk][tn + 0];
            const float b1 = Bs[kk][tn + 1];
            const float b2 = Bs[kk][tn + 2];
            const float b3 = Bs[kk][tn + 3];
            acc[0][0] += a0 * b0; acc[0][1] += a0 * b1; acc[0][2] += a0 * b2; acc[0][3] += a0 * b3;
            acc[1][0] += a1 * b0; acc[1][1] += a1 * b1; acc[1][2] += a1 * b2; acc[1][3] += a1 * b3;
            acc[2][0] += a2 * b0; acc[2][1] += a2 * b1; acc[2][2] += a2 * b2; acc[2][3] += a2 * b3;
            acc[3][0] += a3 * b0; acc[3][1] += a3 * b1; acc[3][2] += a3 * b2; acc[3][3] += a3 * b3;
        }
    }

    const float4 bia = *(const float4*)(bias + n0 + tn);
#pragma unroll
    for (int i = 0; i < 4; ++i) {
        float4 o;
        o.x = acc[i][0] + bia.x;
        o.y = acc[i][1] + bia.y;
        o.z = acc[i][2] + bia.z;
        o.w = acc[i][3] + bia.w;
        *(float4*)(C + (m0 + tm + i) * Dv + n0 + tn) = o;
    }
}

// ---------------------------------------------------------------------------
// Geometric log-bias: LB[b][h][q][m] = log(max(relu(geo.WG+b),1e-6)) + mask
// Block = (b, 4-query tile); thread t = key m. sincos computed once per
// (b,q,m) pair, shared by all 8 heads.
// ---------------------------------------------------------------------------
__global__ __launch_bounds__(256) void geo_bias_kernel(
    const float* __restrict__ box, const int* __restrict__ mask,
    const float* __restrict__ WGw, const float* __restrict__ WGb,
    float* __restrict__ LB)
{
    const int b  = blockIdx.y;
    const int q0 = blockIdx.x * QT;
    const int t  = threadIdx.x;              // key index m

    __shared__ float Wg[Hv * 64];
    __shared__ float Wgb[Hv];
    __shared__ float qgeo[QT][4];

    if (t < Hv) Wgb[t] = WGb[t];
    Wg[t]       = WGw[t];
    Wg[t + 256] = WGw[t + 256];
    if (t < QT) {
        float4 bx = *(const float4*)(box + (b * Nv + q0 + t) * 4);
        qgeo[t][0] = (bx.x + bx.z) * 0.5f;   // cx
        qgeo[t][1] = (bx.y + bx.w) * 0.5f;   // cy
        qgeo[t][2] = bx.z - bx.x + 1.0f;     // w
        qgeo[t][3] = bx.w - bx.y + 1.0f;     // h
    }
    const float4 bm = *(const float4*)(box + (b * Nv + t) * 4);
    const float cxm = (bm.x + bm.z) * 0.5f;
    const float cym = (bm.y + bm.w) * 0.5f;
    const float wm  = bm.z - bm.x + 1.0f;
    const float hm  = bm.w - bm.y + 1.0f;
    const float mterm = (mask[b * Nv + t] == 0) ? -1e9f : 0.0f;
    __syncthreads();

    const float dimm[8] = {1.0f, 0.42169650342f, 0.17782794100f, 0.07498942093f,
                           0.03162277660f, 0.01333521432f, 0.00562341325f, 0.00237137371f};
    for (int q = 0; q < QT; ++q) {
        const float cxq = qgeo[q][0], cyq = qgeo[q][1];
        const float wq  = qgeo[q][2], hq  = qgeo[q][3];
        float delta[4];
        delta[0] = __logf(fmaxf(fabsf((cxq - cxm) / wq), 1e-3f));
        delta[1] = __logf(fmaxf(fabsf((cyq - cym) / hq), 1e-3f));
        delta[2] = __logf(wq / wm);
        delta[3] = __logf(hq / hm);
        float wg[Hv];
#pragma unroll
        for (int h = 0; h < Hv; ++h) wg[h] = Wgb[h];
        for (int d = 0; d < 4; ++d) {
            const float base = 100.0f * delta[d];
#pragma unroll
            for (int j = 0; j < 8; ++j) {
                const float ang = base * dimm[j];
                const float s = sinf(ang);
                const float c = cosf(ang);
                const int idx = d * 8 + j;
#pragma unroll
                for (int h = 0; h < Hv; ++h)
                    wg[h] += s * Wg[h * 64 + idx] + c * Wg[h * 64 + 32 + idx];
            }
        }
#pragma unroll
        for (int h = 0; h < Hv; ++h)
            LB[((b * Hv + h) * Nv + (q0 + q)) * Nv + t] =
                __logf(fmaxf(wg[h], 1e-6f)) + mterm;
    }
}

// ---------------------------------------------------------------------------
// attn2: block = (b, h, 64-query tile), 256 threads, dense LDS-tile GEMMs.
// S^T kept transposed in LDS (St[m][q]) so softmax reads are lane-consecutive
// and PV A-operand reads are 16-lane broadcasts.
// LDS: QTs 17.0K + St 68.0K + KVu 68.0K + red 2.3K = 155.2 KB (1 block/CU).
// ---------------------------------------------------------------------------
__global__ __launch_bounds__(256) void attn2_kernel(
    const float* __restrict__ Q2, const float* __restrict__ K2,
    const float* __restrict__ V2, const float* __restrict__ LB,
    float* __restrict__ CTX)
{
    const int qt = blockIdx.x;   // 0..3
    const int h  = blockIdx.y;   // 0..7
    const int b  = blockIdx.z;   // 0..15
    const int q0 = qt * 64;
    const int t  = threadIdx.x;

    __shared__ float QTs[64][68];        // Q^T tile: QTs[d][q]
    __shared__ float St[256][68];        // scores/probs transposed: St[m][q]
    __shared__ float KVu[256 * 68];      // union: KT[64][132] then Vs[256][68]
    __shared__ float redmax[4][64];
    __shared__ float redsum[4][64];
    __shared__ float rinv[64];

    float* KT = KVu;                     // [d][key], stride 132
    float (*Vs)[68] = (float(*)[68])KVu; // [key][d], stride 68

    // ---- stage Q^T ----
    {
        const int q = t >> 2, f0 = t & 3;
        const float* src = Q2 + (b * Nv + q0 + q) * Dv + h * DKv;
#pragma unroll
        for (int i = 0; i < 4; ++i) {
            const int f = f0 + 4 * i;
            float4 v = *(const float4*)(src + 4 * f);
            QTs[4 * f + 0][q] = v.x;
            QTs[4 * f + 1][q] = v.y;
            QTs[4 * f + 2][q] = v.z;
            QTs[4 * f + 3][q] = v.w;
        }
    }

    const int qrow = t >> 4;   // 0..15 -> q = 4*qrow
    const int mcol = t & 15;   // 0..15 -> m = 4*mcol (+64)

    // ---- scores in two 128-key chunks ----
    for (int c = 0; c < 2; ++c) {
        const int mc = c * 128;
        // stage K^T chunk: KT[d][key]
        {
            const int kf = t & 15;   // float4 index over 64 dims
            const int kk = t >> 4;   // 0..15
#pragma unroll
            for (int p = 0; p < 8; ++p) {
                const int key = p * 16 + kk;   // 0..127
                float4 v = *(const float4*)(K2 + (b * Nv + mc + key) * Dv + h * DKv + 4 * kf);
                KT[(4 * kf + 0) * 132 + key] = v.x;
                KT[(4 * kf + 1) * 132 + key] = v.y;
                KT[(4 * kf + 2) * 132 + key] = v.z;
                KT[(4 * kf + 3) * 132 + key] = v.w;
            }
        }
        __syncthreads();

        float acc[2][4][4] = {};   // [g][qq][i]
#pragma unroll 4
        for (int k = 0; k < 64; ++k) {
            float4 qv = *(const float4*)&QTs[k][4 * qrow];
            float4 k0 = *(const float4*)&KT[k * 132 + 4 * mcol];
            float4 k1 = *(const float4*)&KT[k * 132 + 64 + 4 * mcol];
            const float* qp  = (const float*)&qv;
            const float* k0p = (const float*)&k0;
            const float* k1p = (const float*)&k1;
#pragma unroll
            for (int qq = 0; qq < 4; ++qq)
#pragma unroll
                for (int i = 0; i < 4; ++i) {
                    acc[0][qq][i] += qp[qq] * k0p[i];
                    acc[1][qq][i] += qp[qq] * k1p[i];
                }
        }

        // epilogue: S = acc/8 + LB, write transposed into St[m][q]
        const float* lbbase = LB + ((b * Hv + h) * Nv + (q0 + 4 * qrow)) * Nv + mc + 4 * mcol;
        float4 lb[4][2];
#pragma unroll
        for (int qq = 0; qq < 4; ++qq) {
            lb[qq][0] = *(const float4*)(lbbase + qq * Nv);
            lb[qq][1] = *(const float4*)(lbbase + qq * Nv + 64);
        }
#pragma unroll
        for (int g = 0; g < 2; ++g)
#pragma unroll
            for (int i = 0; i < 4; ++i) {
                float4 v;
                v.x = acc[g][0][i] * 0.125f + ((const float*)&lb[0][g])[i];
                v.y = acc[g][1][i] * 0.125f + ((const float*)&lb[1][g])[i];
                v.z = acc[g][2][i] * 0.125f + ((const float*)&lb[2][g])[i];
                v.w = acc[g][3][i] * 0.125f + ((const float*)&lb[3][g])[i];
                *(float4*)&St[mc + g * 64 + 4 * mcol + i][4 * qrow] = v;
            }
        __syncthreads();   // St chunk done; KT safe to reuse
    }

    // ---- stage V (overwrites KT region) ----
    {
        const int vf = t & 15, vr0 = t >> 4;
#pragma unroll
        for (int p = 0; p < 16; ++p) {
            const int row = p * 16 + vr0;
            float4 v = *(const float4*)(V2 + (b * Nv + row) * Dv + h * DKv + 4 * vf);
            *(float4*)&Vs[row][4 * vf] = v;
        }
    }

    // ---- softmax over m (columns of St) ----
    const int sq = t & 63, mg = t >> 6;
    float mx = -1e30f;
#pragma unroll 8
    for (int i = 0; i < 64; ++i) mx = fmaxf(mx, St[mg * 64 + i][sq]);
    redmax[mg][sq] = mx;
    __syncthreads();
    const float m4 = fmaxf(fmaxf(redmax[0][sq], redmax[1][sq]),
                           fmaxf(redmax[2][sq], redmax[3][sq]));
    float sum = 0.0f;
#pragma unroll 8
    for (int i = 0; i < 64; ++i) {
        const float e = __expf(St[mg * 64 + i][sq] - m4);
        St[mg * 64 + i][sq] = e;
        sum += e;
    }
    redsum[mg][sq] = sum;
    __syncthreads();
    if (t < 64)
        rinv[t] = 1.0f / (redsum[0][t] + redsum[1][t] + redsum[2][t] + redsum[3][t]);
    __syncthreads();

    // ---- PV: O[64x64] = P[64x256] x V[256x64] ----
    const int dcol = t & 15;   // d = 4*dcol
    float acc2[4][4] = {};     // [qq][dd]
#pragma unroll 4
    for (int k = 0; k < 256; ++k) {
        float4 pv = *(const float4*)&St[k][4 * qrow];
        float4 vv = *(const float4*)&Vs[k][4 * dcol];
        const float* pp = (const float*)&pv;
        const float* vp = (const float*)&vv;
#pragma unroll
        for (int qq = 0; qq < 4; ++qq)
#pragma unroll
            for (int dd = 0; dd < 4; ++dd)
                acc2[qq][dd] += pp[qq] * vp[dd];
    }
#pragma unroll
    for (int qq = 0; qq < 4; ++qq) {
        const float s = rinv[4 * qrow + qq];
        float4 o;
        o.x = acc2[qq][0] * s;
        o.y = acc2[qq][1] * s;
        o.z = acc2[qq][2] * s;
        o.w = acc2[qq][3] * s;
        *(float4*)(CTX + (b * Nv + q0 + 4 * qrow + qq) * Dv + h * DKv + 4 * dcol) = o;
    }
}

// ---------------------------------------------------------------------------
extern "C" void kernel_launch(void* const* d_in, const int* in_sizes, int n_in,
                              void* d_out, int out_size, void* d_ws, size_t ws_size,
                              hipStream_t stream) {
    (void)in_sizes; (void)n_in; (void)out_size; (void)ws_size;

    const float* inq  = (const float*)d_in[0];
    const float* ink  = (const float*)d_in[1];
    const float* inv  = (const float*)d_in[2];
    const float* box  = (const float*)d_in[3];
    const int*   mask = (const int*)d_in[4];
    const float* Wq   = (const float*)d_in[5];
    const float* bq   = (const float*)d_in[6];
    const float* Wk   = (const float*)d_in[7];
    const float* bk   = (const float*)d_in[8];
    const float* Wv   = (const float*)d_in[9];
    const float* bv   = (const float*)d_in[10];
    const float* Wo   = (const float*)d_in[11];
    const float* bo   = (const float*)d_in[12];
    const float* WGw  = (const float*)d_in[13];
    const float* WGb  = (const float*)d_in[14];

    float* ws  = (float*)d_ws;
    float* Q2  = ws;                 // [B,N,512]   8 MB
    float* K2  = ws + 2097152;       //             8 MB
    float* V2  = ws + 4194304;       //             8 MB
    float* CTX = ws + 6291456;       //             8 MB
    float* LB  = ws + 8388608;       // [B,H,N,N]  32 MB  (total 64 MB)
    float* out = (float*)d_out;

    dim3 ggrid(Dv / 64, (Bv * Nv) / 64);   // (8, 64)

    geo_bias_kernel<<<dim3(Nv / QT, Bv), 256, 0, stream>>>(box, mask, WGw, WGb, LB);

    gemm_bias_kernel<<<ggrid, 256, 0, stream>>>(inq, Wq, bq, Q2);
    gemm_bias_kernel<<<ggrid, 256, 0, stream>>>(ink, Wk, bk, K2);
    gemm_bias_kernel<<<ggrid, 256, 0, stream>>>(inv, Wv, bv, V2);

    attn2_kernel<<<dim3(Nv / 64, Hv, Bv), 256, 0, stream>>>(Q2, K2, V2, LB, CTX);

    gemm_bias_kernel<<<ggrid, 256, 0, stream>>>(CTX, Wo, bo, out);
}

// Round 3
// 261.479 us; speedup vs baseline: 3.9927x; 1.4365x over previous
//
#include <hip/hip_runtime.h>
#include <hip/hip_fp16.h>
#include <math.h>

#define Bv   16
#define Nv   256
#define Dv   512
#define Hv   8
#define DKv  64
#define QT   4
#define MNv  4096          // B*N tokens

typedef __attribute__((ext_vector_type(8))) short bf16x8;
typedef __attribute__((ext_vector_type(4))) float f32x4;

__device__ __forceinline__ unsigned short f2bf(float f) {   // RNE
    unsigned u = __float_as_uint(f);
    u = u + 0x7FFFu + ((u >> 16) & 1u);
    return (unsigned short)(u >> 16);
}
__device__ __forceinline__ float bf2f(unsigned short h) {
    return __uint_as_float(((unsigned)h) << 16);
}
__device__ __forceinline__ void gload_lds16(const void* g, void* l) {
    __builtin_amdgcn_global_load_lds(
        (const __attribute__((address_space(1))) unsigned int*)g,
        (__attribute__((address_space(3))) unsigned int*)l, 16, 0, 0);
}

// ---------------------------------------------------------------------------
// fp32 -> (hi,lo) bf16 split planes for the 3 projection inputs (z selects).
// ---------------------------------------------------------------------------
__global__ __launch_bounds__(256) void conv_split_kernel(
    const float* __restrict__ xq, const float* __restrict__ xk,
    const float* __restrict__ xv, unsigned short* __restrict__ Ah,
    unsigned short* __restrict__ Al)
{
    const int z = blockIdx.z;
    const float* src = (z == 0) ? xq : (z == 1) ? xk : xv;
    const size_t base = (size_t)z * (MNv * Dv);
    const int idx = (blockIdx.x * 256 + threadIdx.x) * 4;
    float4 x = *(const float4*)(src + idx);
    ushort4 h, l;
    h.x = f2bf(x.x); l.x = f2bf(x.x - bf2f(h.x));
    h.y = f2bf(x.y); l.y = f2bf(x.y - bf2f(h.y));
    h.z = f2bf(x.z); l.z = f2bf(x.z - bf2f(h.z));
    h.w = f2bf(x.w); l.w = f2bf(x.w - bf2f(h.w));
    *(ushort4*)(Ah + base + idx) = h;
    *(ushort4*)(Al + base + idx) = l;
}

// ---------------------------------------------------------------------------
// W[k][n] fp32 -> Wt[n][k] bf16 (transposed), all 4 weights (z); also stacks
// the 4 biases into biasStack[z][512].
// ---------------------------------------------------------------------------
__global__ __launch_bounds__(256) void conv_w_kernel(
    const float* __restrict__ Wq, const float* __restrict__ Wk,
    const float* __restrict__ Wv, const float* __restrict__ Wo,
    const float* __restrict__ bq, const float* __restrict__ bk,
    const float* __restrict__ bv, const float* __restrict__ bo,
    unsigned short* __restrict__ Wt, float* __restrict__ biasStack)
{
    const int z = blockIdx.z;
    const float* W = (z == 0) ? Wq : (z == 1) ? Wk : (z == 2) ? Wv : Wo;
    const float* b = (z == 0) ? bq : (z == 1) ? bk : (z == 2) ? bv : bo;
    const int n0 = blockIdx.x * 64, k0 = blockIdx.y * 64;
    const int t = threadIdx.x;
    __shared__ float T[64][65];
    const int col = t & 63, rb = t >> 6;
#pragma unroll
    for (int i = 0; i < 16; ++i) {
        const int row = i * 4 + rb;
        T[row][col] = W[(k0 + row) * Dv + n0 + col];
    }
    __syncthreads();
#pragma unroll
    for (int i = 0; i < 16; ++i) {
        const int row = i * 4 + rb;
        Wt[z * (Dv * Dv) + (n0 + row) * Dv + k0 + col] = f2bf(T[col][row]);
    }
    if (blockIdx.x == 0 && blockIdx.y == 0) {
        biasStack[z * Dv + t]       = b[t];
        biasStack[z * Dv + t + 256] = b[t + 256];
    }
}

// ---------------------------------------------------------------------------
// MFMA bf16 GEMM: C[4096][512] = (Ah(+Al)) @ Wt^T + bias, fp32 out.
// 128x128 tile, 256 threads (4 waves 2x2), BK=32, global_load_lds width 16.
// ---------------------------------------------------------------------------
template <bool SPLIT>
__global__ __launch_bounds__(256) void mfma_gemm_kernel(
    const unsigned short* __restrict__ Ah, const unsigned short* __restrict__ Al,
    const unsigned short* __restrict__ Wt, const float* __restrict__ bias,
    float* __restrict__ C)
{
    const int z = blockIdx.z;
    Ah   += (size_t)z * (MNv * Dv);
    if (SPLIT) Al += (size_t)z * (MNv * Dv);
    Wt   += z * (Dv * Dv);
    bias += z * Dv;
    C    += (size_t)z * (MNv * Dv);

    const int n0 = blockIdx.x * 128;
    const int m0 = blockIdx.y * 128;
    const int t = threadIdx.x;
    const int w = t >> 6, lane = t & 63;
    const int wm = w & 1, wn = w >> 1;

    __shared__ unsigned short As[128][32];
    __shared__ unsigned short Als[128][32];
    __shared__ unsigned short Bs[128][32];

    f32x4 acc[4][4] = {};

    const int sr = lane >> 2;          // staging row within 16
    const int sk = (lane & 3) * 8;     // staging k offset (elements)
    const int fr = lane & 15;          // frag row/col
    const int fk = (lane >> 4) * 8;    // frag k offset

    for (int k0 = 0; k0 < Dv; k0 += 32) {
        __syncthreads();
#pragma unroll
        for (int j = 0; j < 2; ++j) {
            const int row = w * 32 + j * 16 + sr;
            gload_lds16(Ah + (size_t)(m0 + row) * Dv + k0 + sk, &As[w * 32 + j * 16][0]);
            if (SPLIT)
                gload_lds16(Al + (size_t)(m0 + row) * Dv + k0 + sk, &Als[w * 32 + j * 16][0]);
            gload_lds16(Wt + (size_t)(n0 + row) * Dv + k0 + sk, &Bs[w * 32 + j * 16][0]);
        }
        __syncthreads();

        bf16x8 af[4], bf[4], lf[4];
#pragma unroll
        for (int mt = 0; mt < 4; ++mt)
            af[mt] = *(const bf16x8*)&As[wm * 64 + mt * 16 + fr][fk];
#pragma unroll
        for (int nt = 0; nt < 4; ++nt)
            bf[nt] = *(const bf16x8*)&Bs[wn * 64 + nt * 16 + fr][fk];
        if (SPLIT) {
#pragma unroll
            for (int mt = 0; mt < 4; ++mt)
                lf[mt] = *(const bf16x8*)&Als[wm * 64 + mt * 16 + fr][fk];
        }
#pragma unroll
        for (int mt = 0; mt < 4; ++mt)
#pragma unroll
            for (int nt = 0; nt < 4; ++nt) {
                acc[mt][nt] = __builtin_amdgcn_mfma_f32_16x16x32_bf16(
                    af[mt], bf[nt], acc[mt][nt], 0, 0, 0);
                if (SPLIT)
                    acc[mt][nt] = __builtin_amdgcn_mfma_f32_16x16x32_bf16(
                        lf[mt], bf[nt], acc[mt][nt], 0, 0, 0);
            }
    }

    const int er = (lane >> 4) * 4;    // C row base
    const int ec = lane & 15;          // C col
#pragma unroll
    for (int nt = 0; nt < 4; ++nt) {
        const int gn = n0 + wn * 64 + nt * 16 + ec;
        const float bv_ = bias[gn];
#pragma unroll
        for (int mt = 0; mt < 4; ++mt) {
            const int gm = m0 + wm * 64 + mt * 16 + er;
            float* cp = C + (size_t)gm * Dv + gn;
#pragma unroll
            for (int r = 0; r < 4; ++r)
                cp[(size_t)r * Dv] = acc[mt][nt][r] + bv_;
        }
    }
}

// ---------------------------------------------------------------------------
// Geometric log-bias (f16): LB[b][h][q][m] = log(max(relu(geo.WG+b),1e-6))
// + mask term.  HW __sincosf; sincos once per (b,q,m) for all 8 heads.
// ---------------------------------------------------------------------------
__global__ __launch_bounds__(256) void geo_bias_kernel(
    const float* __restrict__ box, const int* __restrict__ mask,
    const float* __restrict__ WGw, const float* __restrict__ WGb,
    __half* __restrict__ LB)
{
    const int b  = blockIdx.y;
    const int q0 = blockIdx.x * QT;
    const int t  = threadIdx.x;              // key index m

    __shared__ float Wg[Hv * 64];
    __shared__ float Wgb[Hv];
    __shared__ float qgeo[QT][4];

    if (t < Hv) Wgb[t] = WGb[t];
    Wg[t]       = WGw[t];
    Wg[t + 256] = WGw[t + 256];
    if (t < QT) {
        float4 bx = *(const float4*)(box + (b * Nv + q0 + t) * 4);
        qgeo[t][0] = (bx.x + bx.z) * 0.5f;
        qgeo[t][1] = (bx.y + bx.w) * 0.5f;
        qgeo[t][2] = bx.z - bx.x + 1.0f;
        qgeo[t][3] = bx.w - bx.y + 1.0f;
    }
    const float4 bm = *(const float4*)(box + (b * Nv + t) * 4);
    const float cxm = (bm.x + bm.z) * 0.5f;
    const float cym = (bm.y + bm.w) * 0.5f;
    const float wm  = bm.z - bm.x + 1.0f;
    const float hm  = bm.w - bm.y + 1.0f;
    const float mterm = (mask[b * Nv + t] == 0) ? -30000.0f : 0.0f;
    __syncthreads();

    const float dimm[8] = {1.0f, 0.42169650342f, 0.17782794100f, 0.07498942093f,
                           0.03162277660f, 0.01333521432f, 0.00562341325f, 0.00237137371f};
    for (int q = 0; q < QT; ++q) {
        const float cxq = qgeo[q][0], cyq = qgeo[q][1];
        const float wq  = qgeo[q][2], hq  = qgeo[q][3];
        float delta[4];
        delta[0] = __logf(fmaxf(fabsf((cxq - cxm) / wq), 1e-3f));
        delta[1] = __logf(fmaxf(fabsf((cyq - cym) / hq), 1e-3f));
        delta[2] = __logf(wq / wm);
        delta[3] = __logf(hq / hm);
        float wg[Hv];
#pragma unroll
        for (int h = 0; h < Hv; ++h) wg[h] = Wgb[h];
#pragma unroll
        for (int d = 0; d < 4; ++d) {
            const float base = 100.0f * delta[d];
#pragma unroll
            for (int j = 0; j < 8; ++j) {
                float s, c;
                __sincosf(base * dimm[j], &s, &c);
                const int idx = d * 8 + j;
#pragma unroll
                for (int h = 0; h < Hv; ++h)
                    wg[h] += s * Wg[h * 64 + idx] + c * Wg[h * 64 + 32 + idx];
            }
        }
#pragma unroll
        for (int h = 0; h < Hv; ++h)
            LB[((size_t)(b * Hv + h) * Nv + (q0 + q)) * Nv + t] =
                __float2half(__logf(fmaxf(wg[h], 1e-6f)) + mterm);
    }
}

// ---------------------------------------------------------------------------
// attn2: block = (b, h, 64-query tile), 256 threads, dense LDS-tile GEMMs.
// Reads f16 LB, writes bf16 CTX.
// ---------------------------------------------------------------------------
__global__ __launch_bounds__(256) void attn2_kernel(
    const float* __restrict__ Q2, const float* __restrict__ K2,
    const float* __restrict__ V2, const __half* __restrict__ LB,
    unsigned short* __restrict__ CTXb)
{
    const int qt = blockIdx.x;
    const int h  = blockIdx.y;
    const int b  = blockIdx.z;
    const int q0 = qt * 64;
    const int t  = threadIdx.x;

    __shared__ float QTs[64][68];
    __shared__ float St[256][68];
    __shared__ float KVu[256 * 68];
    __shared__ float redmax[4][64];
    __shared__ float redsum[4][64];
    __shared__ float rinv[64];

    float* KT = KVu;
    float (*Vs)[68] = (float(*)[68])KVu;

    {
        const int q = t >> 2, f0 = t & 3;
        const float* src = Q2 + (b * Nv + q0 + q) * Dv + h * DKv;
#pragma unroll
        for (int i = 0; i < 4; ++i) {
            const int f = f0 + 4 * i;
            float4 v = *(const float4*)(src + 4 * f);
            QTs[4 * f + 0][q] = v.x;
            QTs[4 * f + 1][q] = v.y;
            QTs[4 * f + 2][q] = v.z;
            QTs[4 * f + 3][q] = v.w;
        }
    }

    const int qrow = t >> 4;
    const int mcol = t & 15;

    for (int c = 0; c < 2; ++c) {
        const int mc = c * 128;
        {
            const int kf = t & 15;
            const int kk = t >> 4;
#pragma unroll
            for (int p = 0; p < 8; ++p) {
                const int key = p * 16 + kk;
                float4 v = *(const float4*)(K2 + (b * Nv + mc + key) * Dv + h * DKv + 4 * kf);
                KT[(4 * kf + 0) * 132 + key] = v.x;
                KT[(4 * kf + 1) * 132 + key] = v.y;
                KT[(4 * kf + 2) * 132 + key] = v.z;
                KT[(4 * kf + 3) * 132 + key] = v.w;
            }
        }
        __syncthreads();

        float acc[2][4][4] = {};
#pragma unroll 4
        for (int k = 0; k < 64; ++k) {
            float4 qv = *(const float4*)&QTs[k][4 * qrow];
            float4 k0 = *(const float4*)&KT[k * 132 + 4 * mcol];
            float4 k1 = *(const float4*)&KT[k * 132 + 64 + 4 * mcol];
            const float* qp  = (const float*)&qv;
            const float* k0p = (const float*)&k0;
            const float* k1p = (const float*)&k1;
#pragma unroll
            for (int qq = 0; qq < 4; ++qq)
#pragma unroll
                for (int i = 0; i < 4; ++i) {
                    acc[0][qq][i] += qp[qq] * k0p[i];
                    acc[1][qq][i] += qp[qq] * k1p[i];
                }
        }

        const __half* lbbase = LB + ((size_t)(b * Hv + h) * Nv + (q0 + 4 * qrow)) * Nv + mc + 4 * mcol;
        float lbf[4][2][4];
#pragma unroll
        for (int qq = 0; qq < 4; ++qq)
#pragma unroll
            for (int g = 0; g < 2; ++g) {
                const __half2* p = (const __half2*)(lbbase + qq * Nv + g * 64);
                float2 f0 = __half22float2(p[0]);
                float2 f1 = __half22float2(p[1]);
                lbf[qq][g][0] = f0.x; lbf[qq][g][1] = f0.y;
                lbf[qq][g][2] = f1.x; lbf[qq][g][3] = f1.y;
            }
#pragma unroll
        for (int g = 0; g < 2; ++g)
#pragma unroll
            for (int i = 0; i < 4; ++i) {
                float4 v;
                v.x = acc[g][0][i] * 0.125f + lbf[0][g][i];
                v.y = acc[g][1][i] * 0.125f + lbf[1][g][i];
                v.z = acc[g][2][i] * 0.125f + lbf[2][g][i];
                v.w = acc[g][3][i] * 0.125f + lbf[3][g][i];
                *(float4*)&St[mc + g * 64 + 4 * mcol + i][4 * qrow] = v;
            }
        __syncthreads();
    }

    {
        const int vf = t & 15, vr0 = t >> 4;
#pragma unroll
        for (int p = 0; p < 16; ++p) {
            const int row = p * 16 + vr0;
            float4 v = *(const float4*)(V2 + (b * Nv + row) * Dv + h * DKv + 4 * vf);
            *(float4*)&Vs[row][4 * vf] = v;
        }
    }

    const int sq = t & 63, mg = t >> 6;
    float mx = -1e30f;
#pragma unroll 8
    for (int i = 0; i < 64; ++i) mx = fmaxf(mx, St[mg * 64 + i][sq]);
    redmax[mg][sq] = mx;
    __syncthreads();
    const float m4 = fmaxf(fmaxf(redmax[0][sq], redmax[1][sq]),
                           fmaxf(redmax[2][sq], redmax[3][sq]));
    float sum = 0.0f;
#pragma unroll 8
    for (int i = 0; i < 64; ++i) {
        const float e = __expf(St[mg * 64 + i][sq] - m4);
        St[mg * 64 + i][sq] = e;
        sum += e;
    }
    redsum[mg][sq] = sum;
    __syncthreads();
    if (t < 64)
        rinv[t] = 1.0f / (redsum[0][t] + redsum[1][t] + redsum[2][t] + redsum[3][t]);
    __syncthreads();

    const int dcol = t & 15;
    float acc2[4][4] = {};
#pragma unroll 4
    for (int k = 0; k < 256; ++k) {
        float4 pv = *(const float4*)&St[k][4 * qrow];
        float4 vv = *(const float4*)&Vs[k][4 * dcol];
        const float* pp = (const float*)&pv;
        const float* vp = (const float*)&vv;
#pragma unroll
        for (int qq = 0; qq < 4; ++qq)
#pragma unroll
            for (int dd = 0; dd < 4; ++dd)
                acc2[qq][dd] += pp[qq] * vp[dd];
    }
#pragma unroll
    for (int qq = 0; qq < 4; ++qq) {
        const float s = rinv[4 * qrow + qq];
        ushort4 ob;
        ob.x = f2bf(acc2[qq][0] * s);
        ob.y = f2bf(acc2[qq][1] * s);
        ob.z = f2bf(acc2[qq][2] * s);
        ob.w = f2bf(acc2[qq][3] * s);
        *(ushort4*)(CTXb + (size_t)(b * Nv + q0 + 4 * qrow + qq) * Dv + h * DKv + 4 * dcol) = ob;
    }
}

// ---------------------------------------------------------------------------
extern "C" void kernel_launch(void* const* d_in, const int* in_sizes, int n_in,
                              void* d_out, int out_size, void* d_ws, size_t ws_size,
                              hipStream_t stream) {
    (void)in_sizes; (void)n_in; (void)out_size; (void)ws_size;

    const float* inq  = (const float*)d_in[0];
    const float* ink  = (const float*)d_in[1];
    const float* inv  = (const float*)d_in[2];
    const float* box  = (const float*)d_in[3];
    const int*   mask = (const int*)d_in[4];
    const float* Wq   = (const float*)d_in[5];
    const float* bq   = (const float*)d_in[6];
    const float* Wk   = (const float*)d_in[7];
    const float* bk   = (const float*)d_in[8];
    const float* Wv   = (const float*)d_in[9];
    const float* bv   = (const float*)d_in[10];
    const float* Wo   = (const float*)d_in[11];
    const float* bo   = (const float*)d_in[12];
    const float* WGw  = (const float*)d_in[13];
    const float* WGb  = (const float*)d_in[14];

    char* W = (char*)d_ws;
    float*          Q2   = (float*)(W + 0);                    //  8 MB fp32 (Q2,K2,V2 contiguous)
    float*          K2   = (float*)(W + 8388608);
    float*          V2   = (float*)(W + 16777216);
    unsigned short* Ah   = (unsigned short*)(W + 25165824);    // 12 MB (3 planes)
    unsigned short* Al   = (unsigned short*)(W + 37748736);    // 12 MB
    __half*         LB   = (__half*)(W + 25165824);            // 16.8 MB, aliases Ah/Al (dead after QKV)
    unsigned short* Wt   = (unsigned short*)(W + 50331648);    //  2 MB (4 transposed weights)
    float*          bst  = (float*)(W + 52428800);             //  8 KB bias stack
    unsigned short* CTXb = (unsigned short*)(W + 53477376);    //  4 MB
    float*          out  = (float*)d_out;

    conv_split_kernel<<<dim3(2048, 1, 3), 256, 0, stream>>>(inq, ink, inv, Ah, Al);
    conv_w_kernel<<<dim3(8, 8, 4), 256, 0, stream>>>(Wq, Wk, Wv, Wo, bq, bk, bv, bo, Wt, bst);

    mfma_gemm_kernel<true><<<dim3(4, 32, 3), 256, 0, stream>>>(Ah, Al, Wt, bst, Q2);

    geo_bias_kernel<<<dim3(Nv / QT, Bv), 256, 0, stream>>>(box, mask, WGw, WGb, LB);

    attn2_kernel<<<dim3(Nv / 64, Hv, Bv), 256, 0, stream>>>(Q2, K2, V2, LB, CTXb);

    mfma_gemm_kernel<false><<<dim3(4, 32, 1), 256, 0, stream>>>(
        CTXb, CTXb, Wt + 3 * (Dv * Dv), bst + 3 * Dv, out);
}

// Round 4
// 226.423 us; speedup vs baseline: 4.6109x; 1.1548x over previous
//
#include <hip/hip_runtime.h>
#include <hip/hip_fp16.h>
#include <math.h>

#define Bv   16
#define Nv   256
#define Dv   512
#define Hv   8
#define DKv  64
#define QT   4
#define MNv  4096          // B*N tokens

typedef __attribute__((ext_vector_type(8))) short bf16x8;
typedef __attribute__((ext_vector_type(4))) float f32x4;
typedef __fp16 fp16x8 __attribute__((ext_vector_type(8)));

__device__ __forceinline__ unsigned short f2bf(float f) {   // RNE
    unsigned u = __float_as_uint(f);
    u = u + 0x7FFFu + ((u >> 16) & 1u);
    return (unsigned short)(u >> 16);
}
__device__ __forceinline__ float bf2f(unsigned short h) {
    return __uint_as_float(((unsigned)h) << 16);
}
__device__ __forceinline__ void gload_lds16(const void* g, void* l) {
    __builtin_amdgcn_global_load_lds(
        (const __attribute__((address_space(1))) unsigned int*)g,
        (__attribute__((address_space(3))) unsigned int*)l, 16, 0, 0);
}

// ---------------------------------------------------------------------------
// fp32 -> (hi,lo) bf16 split planes for the 3 projection inputs (z selects).
// ---------------------------------------------------------------------------
__global__ __launch_bounds__(256) void conv_split_kernel(
    const float* __restrict__ xq, const float* __restrict__ xk,
    const float* __restrict__ xv, unsigned short* __restrict__ Ah,
    unsigned short* __restrict__ Al)
{
    const int z = blockIdx.z;
    const float* src = (z == 0) ? xq : (z == 1) ? xk : xv;
    const size_t base = (size_t)z * (MNv * Dv);
    const int idx = (blockIdx.x * 256 + threadIdx.x) * 4;
    float4 x = *(const float4*)(src + idx);
    ushort4 h, l;
    h.x = f2bf(x.x); l.x = f2bf(x.x - bf2f(h.x));
    h.y = f2bf(x.y); l.y = f2bf(x.y - bf2f(h.y));
    h.z = f2bf(x.z); l.z = f2bf(x.z - bf2f(h.z));
    h.w = f2bf(x.w); l.w = f2bf(x.w - bf2f(h.w));
    *(ushort4*)(Ah + base + idx) = h;
    *(ushort4*)(Al + base + idx) = l;
}

// ---------------------------------------------------------------------------
// W[k][n] fp32 -> Wt[n][k] bf16 (transposed), all 4 weights (z); also stacks
// the 4 biases into biasStack[z][512].
// ---------------------------------------------------------------------------
__global__ __launch_bounds__(256) void conv_w_kernel(
    const float* __restrict__ Wq, const float* __restrict__ Wk,
    const float* __restrict__ Wv, const float* __restrict__ Wo,
    const float* __restrict__ bq, const float* __restrict__ bk,
    const float* __restrict__ bv, const float* __restrict__ bo,
    unsigned short* __restrict__ Wt, float* __restrict__ biasStack)
{
    const int z = blockIdx.z;
    const float* W = (z == 0) ? Wq : (z == 1) ? Wk : (z == 2) ? Wv : Wo;
    const float* b = (z == 0) ? bq : (z == 1) ? bk : (z == 2) ? bv : bo;
    const int n0 = blockIdx.x * 64, k0 = blockIdx.y * 64;
    const int t = threadIdx.x;
    __shared__ float T[64][65];
    const int col = t & 63, rb = t >> 6;
#pragma unroll
    for (int i = 0; i < 16; ++i) {
        const int row = i * 4 + rb;
        T[row][col] = W[(k0 + row) * Dv + n0 + col];
    }
    __syncthreads();
#pragma unroll
    for (int i = 0; i < 16; ++i) {
        const int row = i * 4 + rb;
        Wt[z * (Dv * Dv) + (n0 + row) * Dv + k0 + col] = f2bf(T[col][row]);
    }
    if (blockIdx.x == 0 && blockIdx.y == 0) {
        biasStack[z * Dv + t]       = b[t];
        biasStack[z * Dv + t + 256] = b[t + 256];
    }
}

// ---------------------------------------------------------------------------
// MFMA bf16 GEMM: C[4096][512] = (Ah(+Al)) @ Wt^T + bias, fp32 out.
// 128x128 tile, 256 threads (4 waves 2x2), BK=32, global_load_lds width 16.
// ---------------------------------------------------------------------------
template <bool SPLIT>
__global__ __launch_bounds__(256) void mfma_gemm_kernel(
    const unsigned short* __restrict__ Ah, const unsigned short* __restrict__ Al,
    const unsigned short* __restrict__ Wt, const float* __restrict__ bias,
    float* __restrict__ C)
{
    const int z = blockIdx.z;
    Ah   += (size_t)z * (MNv * Dv);
    if (SPLIT) Al += (size_t)z * (MNv * Dv);
    Wt   += z * (Dv * Dv);
    bias += z * Dv;
    C    += (size_t)z * (MNv * Dv);

    const int n0 = blockIdx.x * 128;
    const int m0 = blockIdx.y * 128;
    const int t = threadIdx.x;
    const int w = t >> 6, lane = t & 63;
    const int wm = w & 1, wn = w >> 1;

    __shared__ unsigned short As[128][32];
    __shared__ unsigned short Als[128][32];
    __shared__ unsigned short Bs[128][32];

    f32x4 acc[4][4] = {};

    const int sr = lane >> 2;          // staging row within 16
    const int sk = (lane & 3) * 8;     // staging k offset (elements)
    const int fr = lane & 15;          // frag row/col
    const int fk = (lane >> 4) * 8;    // frag k offset

    for (int k0 = 0; k0 < Dv; k0 += 32) {
        __syncthreads();
#pragma unroll
        for (int j = 0; j < 2; ++j) {
            const int row = w * 32 + j * 16 + sr;
            gload_lds16(Ah + (size_t)(m0 + row) * Dv + k0 + sk, &As[w * 32 + j * 16][0]);
            if (SPLIT)
                gload_lds16(Al + (size_t)(m0 + row) * Dv + k0 + sk, &Als[w * 32 + j * 16][0]);
            gload_lds16(Wt + (size_t)(n0 + row) * Dv + k0 + sk, &Bs[w * 32 + j * 16][0]);
        }
        __syncthreads();

        bf16x8 af[4], bf[4], lf[4];
#pragma unroll
        for (int mt = 0; mt < 4; ++mt)
            af[mt] = *(const bf16x8*)&As[wm * 64 + mt * 16 + fr][fk];
#pragma unroll
        for (int nt = 0; nt < 4; ++nt)
            bf[nt] = *(const bf16x8*)&Bs[wn * 64 + nt * 16 + fr][fk];
        if (SPLIT) {
#pragma unroll
            for (int mt = 0; mt < 4; ++mt)
                lf[mt] = *(const bf16x8*)&Als[wm * 64 + mt * 16 + fr][fk];
        }
#pragma unroll
        for (int mt = 0; mt < 4; ++mt)
#pragma unroll
            for (int nt = 0; nt < 4; ++nt) {
                acc[mt][nt] = __builtin_amdgcn_mfma_f32_16x16x32_bf16(
                    af[mt], bf[nt], acc[mt][nt], 0, 0, 0);
                if (SPLIT)
                    acc[mt][nt] = __builtin_amdgcn_mfma_f32_16x16x32_bf16(
                        lf[mt], bf[nt], acc[mt][nt], 0, 0, 0);
            }
    }

    const int er = (lane >> 4) * 4;    // C row base
    const int ec = lane & 15;          // C col
#pragma unroll
    for (int nt = 0; nt < 4; ++nt) {
        const int gn = n0 + wn * 64 + nt * 16 + ec;
        const float bv_ = bias[gn];
#pragma unroll
        for (int mt = 0; mt < 4; ++mt) {
            const int gm = m0 + wm * 64 + mt * 16 + er;
            float* cp = C + (size_t)gm * Dv + gn;
#pragma unroll
            for (int r = 0; r < 4; ++r)
                cp[(size_t)r * Dv] = acc[mt][nt][r] + bv_;
        }
    }
}

// ---------------------------------------------------------------------------
// Geometric log-bias via MFMA.  Block=(q,b), 256 thr = 4 waves, no LDS.
// Wave-tile: 16 keys x 16 heads (8 real).  A-frag structure == embedding
// structure: lane quad = delta component, j = frequency -> each lane computes
// ONE delta + 8 sincos straight into its A fragment.  hi/lo f16 split on both
// A and W (3 MFMAs per K=32 chunk) keeps the dot fp32-accurate.
// ---------------------------------------------------------------------------
__global__ __launch_bounds__(256) void geo_mfma_kernel(
    const float* __restrict__ box, const int* __restrict__ mask,
    const float* __restrict__ WGw, const float* __restrict__ WGb,
    __half* __restrict__ LB)
{
    const int q = blockIdx.x;
    const int b = blockIdx.y;
    const int t = threadIdx.x;
    const int w = t >> 6, lane = t & 63;
    const int n = lane & 15;           // head col (B/C) and A-row-within-16
    const int quad = lane >> 4;        // delta component / k-chunk

    // query geometry (wave-uniform)
    const float4 bq_ = *(const float4*)(box + (b * Nv + q) * 4);
    const float cxq = (bq_.x + bq_.z) * 0.5f;
    const float cyq = (bq_.y + bq_.w) * 0.5f;
    const float wq  = bq_.z - bq_.x + 1.0f;
    const float hq  = bq_.w - bq_.y + 1.0f;

    // B fragments: WGw[n][quad*8+j] (sin dims) / WGw[n][32+quad*8+j] (cos)
    fp16x8 Bh0 = {}, Bl0 = {}, Bh1 = {}, Bl1 = {};
    float bias_n = 0.0f;
    if (n < Hv) {
        bias_n = WGb[n];
#pragma unroll
        for (int j = 0; j < 8; ++j) {
            const float w0 = WGw[n * 64 + quad * 8 + j];
            const float w1 = WGw[n * 64 + 32 + quad * 8 + j];
            const __fp16 h0 = (__fp16)w0;
            const __fp16 h1 = (__fp16)w1;
            Bh0[j] = h0; Bl0[j] = (__fp16)(w0 - (float)h0);
            Bh1[j] = h1; Bl1[j] = (__fp16)(w1 - (float)h1);
        }
    }

    const float dimm[8] = {1.0f, 0.42169650342f, 0.17782794100f, 0.07498942093f,
                           0.03162277660f, 0.01333521432f, 0.00562341325f, 0.00237137371f};
    const bool isCtr = (quad < 2);
    const bool isY   = (quad & 1);
    const float cq  = isY ? cyq : cxq;
    const float sq_ = isY ? hq : wq;

    for (int i = 0; i < 4; ++i) {
        const int m0 = (w * 4 + i) * 16;
        // key geometry for this lane's A-row pair
        const float4 bm = *(const float4*)(box + (b * Nv + m0 + n) * 4);
        const float cxm = (bm.x + bm.z) * 0.5f;
        const float cym = (bm.y + bm.w) * 0.5f;
        const float wm  = bm.z - bm.x + 1.0f;
        const float hm  = bm.w - bm.y + 1.0f;
        const float cm_ = isY ? cym : cxm;
        const float sm_ = isY ? hm : wm;
        const float top = isCtr ? fabsf(cq - cm_) : sq_;
        const float bot = isCtr ? sq_ : sm_;
        float r = top / bot;
        if (isCtr) r = fmaxf(r, 1e-3f);
        const float base = 100.0f * __logf(r);

        fp16x8 Ash, Asl, Ach, Acl;
#pragma unroll
        for (int j = 0; j < 8; ++j) {
            float s, c;
            __sincosf(base * dimm[j], &s, &c);
            const __fp16 hs = (__fp16)s;
            const __fp16 hc = (__fp16)c;
            Ash[j] = hs; Asl[j] = (__fp16)(s - (float)hs);
            Ach[j] = hc; Acl[j] = (__fp16)(c - (float)hc);
        }

        f32x4 acc = {};
        acc = __builtin_amdgcn_mfma_f32_16x16x32_f16(Ash, Bh0, acc, 0, 0, 0);
        acc = __builtin_amdgcn_mfma_f32_16x16x32_f16(Asl, Bh0, acc, 0, 0, 0);
        acc = __builtin_amdgcn_mfma_f32_16x16x32_f16(Ash, Bl0, acc, 0, 0, 0);
        acc = __builtin_amdgcn_mfma_f32_16x16x32_f16(Ach, Bh1, acc, 0, 0, 0);
        acc = __builtin_amdgcn_mfma_f32_16x16x32_f16(Acl, Bh1, acc, 0, 0, 0);
        acc = __builtin_amdgcn_mfma_f32_16x16x32_f16(Ach, Bl1, acc, 0, 0, 0);

        // epilogue: C row = m0+quad*4+r (key), col = n (head)
        const int mrow = m0 + quad * 4;
        const int4 mk = *(const int4*)(mask + b * Nv + mrow);
        if (n < Hv) {
            const int* mkp = (const int*)&mk;
            ushort4 o;
            unsigned short os[4];
#pragma unroll
            for (int rr = 0; rr < 4; ++rr) {
                const float val = fmaxf(acc[rr] + bias_n, 1e-6f);
                const float lb = __logf(val) + (mkp[rr] ? 0.0f : -30000.0f);
                os[rr] = __half_as_ushort(__float2half(lb));
            }
            o.x = os[0]; o.y = os[1]; o.z = os[2]; o.w = os[3];
            *(ushort4*)((unsigned short*)LB +
                        ((size_t)(b * Hv + n) * Nv + q) * Nv + mrow) = o;
        }
    }
}

// ---------------------------------------------------------------------------
// attn2: block = (b, h, 64-query tile), 256 threads, dense LDS-tile GEMMs.
// Reads f16 LB, writes bf16 CTX.
// ---------------------------------------------------------------------------
__global__ __launch_bounds__(256) void attn2_kernel(
    const float* __restrict__ Q2, const float* __restrict__ K2,
    const float* __restrict__ V2, const __half* __restrict__ LB,
    unsigned short* __restrict__ CTXb)
{
    const int qt = blockIdx.x;
    const int h  = blockIdx.y;
    const int b  = blockIdx.z;
    const int q0 = qt * 64;
    const int t  = threadIdx.x;

    __shared__ float QTs[64][68];
    __shared__ float St[256][68];
    __shared__ float KVu[256 * 68];
    __shared__ float redmax[4][64];
    __shared__ float redsum[4][64];
    __shared__ float rinv[64];

    float* KT = KVu;
    float (*Vs)[68] = (float(*)[68])KVu;

    {
        const int q = t >> 2, f0 = t & 3;
        const float* src = Q2 + (b * Nv + q0 + q) * Dv + h * DKv;
#pragma unroll
        for (int i = 0; i < 4; ++i) {
            const int f = f0 + 4 * i;
            float4 v = *(const float4*)(src + 4 * f);
            QTs[4 * f + 0][q] = v.x;
            QTs[4 * f + 1][q] = v.y;
            QTs[4 * f + 2][q] = v.z;
            QTs[4 * f + 3][q] = v.w;
        }
    }

    const int qrow = t >> 4;
    const int mcol = t & 15;

    for (int c = 0; c < 2; ++c) {
        const int mc = c * 128;
        {
            const int kf = t & 15;
            const int kk = t >> 4;
#pragma unroll
            for (int p = 0; p < 8; ++p) {
                const int key = p * 16 + kk;
                float4 v = *(const float4*)(K2 + (b * Nv + mc + key) * Dv + h * DKv + 4 * kf);
                KT[(4 * kf + 0) * 132 + key] = v.x;
                KT[(4 * kf + 1) * 132 + key] = v.y;
                KT[(4 * kf + 2) * 132 + key] = v.z;
                KT[(4 * kf + 3) * 132 + key] = v.w;
            }
        }
        __syncthreads();

        float acc[2][4][4] = {};
#pragma unroll 4
        for (int k = 0; k < 64; ++k) {
            float4 qv = *(const float4*)&QTs[k][4 * qrow];
            float4 k0 = *(const float4*)&KT[k * 132 + 4 * mcol];
            float4 k1 = *(const float4*)&KT[k * 132 + 64 + 4 * mcol];
            const float* qp  = (const float*)&qv;
            const float* k0p = (const float*)&k0;
            const float* k1p = (const float*)&k1;
#pragma unroll
            for (int qq = 0; qq < 4; ++qq)
#pragma unroll
                for (int i = 0; i < 4; ++i) {
                    acc[0][qq][i] += qp[qq] * k0p[i];
                    acc[1][qq][i] += qp[qq] * k1p[i];
                }
        }

        const __half* lbbase = LB + ((size_t)(b * Hv + h) * Nv + (q0 + 4 * qrow)) * Nv + mc + 4 * mcol;
        float lbf[4][2][4];
#pragma unroll
        for (int qq = 0; qq < 4; ++qq)
#pragma unroll
            for (int g = 0; g < 2; ++g) {
                const __half2* p = (const __half2*)(lbbase + qq * Nv + g * 64);
                float2 f0 = __half22float2(p[0]);
                float2 f1 = __half22float2(p[1]);
                lbf[qq][g][0] = f0.x; lbf[qq][g][1] = f0.y;
                lbf[qq][g][2] = f1.x; lbf[qq][g][3] = f1.y;
            }
#pragma unroll
        for (int g = 0; g < 2; ++g)
#pragma unroll
            for (int i = 0; i < 4; ++i) {
                float4 v;
                v.x = acc[g][0][i] * 0.125f + lbf[0][g][i];
                v.y = acc[g][1][i] * 0.125f + lbf[1][g][i];
                v.z = acc[g][2][i] * 0.125f + lbf[2][g][i];
                v.w = acc[g][3][i] * 0.125f + lbf[3][g][i];
                *(float4*)&St[mc + g * 64 + 4 * mcol + i][4 * qrow] = v;
            }
        __syncthreads();
    }

    {
        const int vf = t & 15, vr0 = t >> 4;
#pragma unroll
        for (int p = 0; p < 16; ++p) {
            const int row = p * 16 + vr0;
            float4 v = *(const float4*)(V2 + (b * Nv + row) * Dv + h * DKv + 4 * vf);
            *(float4*)&Vs[row][4 * vf] = v;
        }
    }

    const int sq = t & 63, mg = t >> 6;
    float mx = -1e30f;
#pragma unroll 8
    for (int i = 0; i < 64; ++i) mx = fmaxf(mx, St[mg * 64 + i][sq]);
    redmax[mg][sq] = mx;
    __syncthreads();
    const float m4 = fmaxf(fmaxf(redmax[0][sq], redmax[1][sq]),
                           fmaxf(redmax[2][sq], redmax[3][sq]));
    float sum = 0.0f;
#pragma unroll 8
    for (int i = 0; i < 64; ++i) {
        const float e = __expf(St[mg * 64 + i][sq] - m4);
        St[mg * 64 + i][sq] = e;
        sum += e;
    }
    redsum[mg][sq] = sum;
    __syncthreads();
    if (t < 64)
        rinv[t] = 1.0f / (redsum[0][t] + redsum[1][t] + redsum[2][t] + redsum[3][t]);
    __syncthreads();

    const int dcol = t & 15;
    float acc2[4][4] = {};
#pragma unroll 4
    for (int k = 0; k < 256; ++k) {
        float4 pv = *(const float4*)&St[k][4 * qrow];
        float4 vv = *(const float4*)&Vs[k][4 * dcol];
        const float* pp = (const float*)&pv;
        const float* vp = (const float*)&vv;
#pragma unroll
        for (int qq = 0; qq < 4; ++qq)
#pragma unroll
            for (int dd = 0; dd < 4; ++dd)
                acc2[qq][dd] += pp[qq] * vp[dd];
    }
#pragma unroll
    for (int qq = 0; qq < 4; ++qq) {
        const float s = rinv[4 * qrow + qq];
        ushort4 ob;
        ob.x = f2bf(acc2[qq][0] * s);
        ob.y = f2bf(acc2[qq][1] * s);
        ob.z = f2bf(acc2[qq][2] * s);
        ob.w = f2bf(acc2[qq][3] * s);
        *(ushort4*)(CTXb + (size_t)(b * Nv + q0 + 4 * qrow + qq) * Dv + h * DKv + 4 * dcol) = ob;
    }
}

// ---------------------------------------------------------------------------
extern "C" void kernel_launch(void* const* d_in, const int* in_sizes, int n_in,
                              void* d_out, int out_size, void* d_ws, size_t ws_size,
                              hipStream_t stream) {
    (void)in_sizes; (void)n_in; (void)out_size; (void)ws_size;

    const float* inq  = (const float*)d_in[0];
    const float* ink  = (const float*)d_in[1];
    const float* inv  = (const float*)d_in[2];
    const float* box  = (const float*)d_in[3];
    const int*   mask = (const int*)d_in[4];
    const float* Wq   = (const float*)d_in[5];
    const float* bq   = (const float*)d_in[6];
    const float* Wk   = (const float*)d_in[7];
    const float* bk   = (const float*)d_in[8];
    const float* Wv   = (const float*)d_in[9];
    const float* bv   = (const float*)d_in[10];
    const float* Wo   = (const float*)d_in[11];
    const float* bo   = (const float*)d_in[12];
    const float* WGw  = (const float*)d_in[13];
    const float* WGb  = (const float*)d_in[14];

    char* W = (char*)d_ws;
    float*          Q2   = (float*)(W + 0);                    //  8 MB fp32 (Q2,K2,V2 contiguous)
    float*          K2   = (float*)(W + 8388608);
    float*          V2   = (float*)(W + 16777216);
    unsigned short* Ah   = (unsigned short*)(W + 25165824);    // 12 MB (3 planes)
    unsigned short* Al   = (unsigned short*)(W + 37748736);    // 12 MB
    __half*         LB   = (__half*)(W + 25165824);            // 16.8 MB, aliases Ah/Al (dead after QKV)
    unsigned short* Wt   = (unsigned short*)(W + 50331648);    //  2 MB (4 transposed weights)
    float*          bst  = (float*)(W + 52428800);             //  8 KB bias stack
    unsigned short* CTXb = (unsigned short*)(W + 53477376);    //  4 MB
    float*          out  = (float*)d_out;

    conv_split_kernel<<<dim3(2048, 1, 3), 256, 0, stream>>>(inq, ink, inv, Ah, Al);
    conv_w_kernel<<<dim3(8, 8, 4), 256, 0, stream>>>(Wq, Wk, Wv, Wo, bq, bk, bv, bo, Wt, bst);

    mfma_gemm_kernel<true><<<dim3(4, 32, 3), 256, 0, stream>>>(Ah, Al, Wt, bst, Q2);

    geo_mfma_kernel<<<dim3(Nv, Bv), 256, 0, stream>>>(box, mask, WGw, WGb, LB);

    attn2_kernel<<<dim3(Nv / 64, Hv, Bv), 256, 0, stream>>>(Q2, K2, V2, LB, CTXb);

    mfma_gemm_kernel<false><<<dim3(4, 32, 1), 256, 0, stream>>>(
        CTXb, CTXb, Wt + 3 * (Dv * Dv), bst + 3 * Dv, out);
}

// Round 5
// 196.633 us; speedup vs baseline: 5.3094x; 1.1515x over previous
//
#include <hip/hip_runtime.h>
#include <hip/hip_fp16.h>
#include <math.h>

#define Bv   16
#define Nv   256
#define Dv   512
#define Hv   8
#define MNv  4096          // B*N tokens

typedef __attribute__((ext_vector_type(8))) short bf16x8;
typedef __attribute__((ext_vector_type(4))) float f32x4;
typedef __fp16 fp16x8 __attribute__((ext_vector_type(8)));

__device__ __forceinline__ unsigned short f2bf(float f) {   // RNE
    unsigned u = __float_as_uint(f);
    u = u + 0x7FFFu + ((u >> 16) & 1u);
    return (unsigned short)(u >> 16);
}
__device__ __forceinline__ float bf2f(unsigned short h) {
    return __uint_as_float(((unsigned)h) << 16);
}
__device__ __forceinline__ void gload_lds16(const void* g, void* l) {
    __builtin_amdgcn_global_load_lds(
        (const __attribute__((address_space(1))) unsigned int*)g,
        (__attribute__((address_space(3))) unsigned int*)l, 16, 0, 0);
}

// ---------------------------------------------------------------------------
// fp32 -> bf16 for the 3 projection inputs (z selects). No hi/lo split.
// ---------------------------------------------------------------------------
__global__ __launch_bounds__(256) void conv_b16_kernel(
    const float* __restrict__ xq, const float* __restrict__ xk,
    const float* __restrict__ xv, unsigned short* __restrict__ Ab)
{
    const int z = blockIdx.z;
    const float* src = (z == 0) ? xq : (z == 1) ? xk : xv;
    const size_t base = (size_t)z * (MNv * Dv);
    const int idx = (blockIdx.x * 256 + threadIdx.x) * 4;
    float4 x = *(const float4*)(src + idx);
    ushort4 h;
    h.x = f2bf(x.x); h.y = f2bf(x.y); h.z = f2bf(x.z); h.w = f2bf(x.w);
    *(ushort4*)(Ab + base + idx) = h;
}

// ---------------------------------------------------------------------------
// W[k][n] fp32 -> Wt[n][k] bf16 (transposed), all 4 weights (z); also stacks
// the 4 biases into biasStack[z][512].
// ---------------------------------------------------------------------------
__global__ __launch_bounds__(256) void conv_w_kernel(
    const float* __restrict__ Wq, const float* __restrict__ Wk,
    const float* __restrict__ Wv, const float* __restrict__ Wo,
    const float* __restrict__ bq, const float* __restrict__ bk,
    const float* __restrict__ bv, const float* __restrict__ bo,
    unsigned short* __restrict__ Wt, float* __restrict__ biasStack)
{
    const int z = blockIdx.z;
    const float* W = (z == 0) ? Wq : (z == 1) ? Wk : (z == 2) ? Wv : Wo;
    const float* b = (z == 0) ? bq : (z == 1) ? bk : (z == 2) ? bv : bo;
    const int n0 = blockIdx.x * 64, k0 = blockIdx.y * 64;
    const int t = threadIdx.x;
    __shared__ float T[64][65];
    const int col = t & 63, rb = t >> 6;
#pragma unroll
    for (int i = 0; i < 16; ++i) {
        const int row = i * 4 + rb;
        T[row][col] = W[(k0 + row) * Dv + n0 + col];
    }
    __syncthreads();
#pragma unroll
    for (int i = 0; i < 16; ++i) {
        const int row = i * 4 + rb;
        Wt[z * (Dv * Dv) + (n0 + row) * Dv + k0 + col] = f2bf(T[col][row]);
    }
    if (blockIdx.x == 0 && blockIdx.y == 0) {
        biasStack[z * Dv + t]       = b[t];
        biasStack[z * Dv + t + 256] = b[t + 256];
    }
}

// ---------------------------------------------------------------------------
// MFMA bf16 GEMM: C[4096][512] = A @ Wt^T + bias.
// MODE 0: fp32 out row-major.  MODE 1: bf16 out row-major, scaled.
// MODE 2: bf16 out transposed per-batch-of-256: C[b][n][m].
// 128x128 tile, 256 threads (4 waves 2x2), BK=32, global_load_lds width 16.
// ---------------------------------------------------------------------------
template <int MODE>
__global__ __launch_bounds__(256) void mfma_gemm2(
    const unsigned short* __restrict__ A, const unsigned short* __restrict__ Wt,
    const float* __restrict__ bias, void* __restrict__ Cout, float scale)
{
    const int n0 = blockIdx.x * 128;
    const int m0 = blockIdx.y * 128;
    const int t = threadIdx.x;
    const int w = t >> 6, lane = t & 63;
    const int wm = w & 1, wn = w >> 1;

    __shared__ unsigned short As[128][32];
    __shared__ unsigned short Bs[128][32];

    f32x4 acc[4][4] = {};

    const int sr = lane >> 2;          // staging row within 16
    const int sk = (lane & 3) * 8;     // staging k offset (elements)
    const int fr = lane & 15;          // frag row/col
    const int fk = (lane >> 4) * 8;    // frag k offset

    for (int k0 = 0; k0 < Dv; k0 += 32) {
        __syncthreads();
#pragma unroll
        for (int j = 0; j < 2; ++j) {
            const int row = w * 32 + j * 16 + sr;
            gload_lds16(A + (size_t)(m0 + row) * Dv + k0 + sk, &As[w * 32 + j * 16][0]);
            gload_lds16(Wt + (size_t)(n0 + row) * Dv + k0 + sk, &Bs[w * 32 + j * 16][0]);
        }
        __syncthreads();

        bf16x8 af[4], bfr[4];
#pragma unroll
        for (int mt = 0; mt < 4; ++mt)
            af[mt] = *(const bf16x8*)&As[wm * 64 + mt * 16 + fr][fk];
#pragma unroll
        for (int nt = 0; nt < 4; ++nt)
            bfr[nt] = *(const bf16x8*)&Bs[wn * 64 + nt * 16 + fr][fk];
#pragma unroll
        for (int mt = 0; mt < 4; ++mt)
#pragma unroll
            for (int nt = 0; nt < 4; ++nt)
                acc[mt][nt] = __builtin_amdgcn_mfma_f32_16x16x32_bf16(
                    af[mt], bfr[nt], acc[mt][nt], 0, 0, 0);
    }

    const int er = (lane >> 4) * 4;
    const int ec = lane & 15;
#pragma unroll
    for (int nt = 0; nt < 4; ++nt) {
        const int gn = n0 + wn * 64 + nt * 16 + ec;
        const float bv_ = bias[gn];
#pragma unroll
        for (int mt = 0; mt < 4; ++mt) {
            const int gm = m0 + wm * 64 + mt * 16 + er;
            if (MODE == 0) {
                float* cp = (float*)Cout + (size_t)gm * Dv + gn;
#pragma unroll
                for (int r = 0; r < 4; ++r)
                    cp[(size_t)r * Dv] = acc[mt][nt][r] + bv_;
            } else if (MODE == 1) {
                unsigned short* cp = (unsigned short*)Cout + (size_t)gm * Dv + gn;
#pragma unroll
                for (int r = 0; r < 4; ++r)
                    cp[(size_t)r * Dv] = f2bf((acc[mt][nt][r] + bv_) * scale);
            } else {
                ushort4 o;
                o.x = f2bf(acc[mt][nt][0] + bv_);
                o.y = f2bf(acc[mt][nt][1] + bv_);
                o.z = f2bf(acc[mt][nt][2] + bv_);
                o.w = f2bf(acc[mt][nt][3] + bv_);
                *(ushort4*)((unsigned short*)Cout +
                            ((size_t)(gm >> 8) * Dv + gn) * Nv + (gm & 255)) = o;
            }
        }
    }
}

// ---------------------------------------------------------------------------
// Geometric log-bias via MFMA.  Block=(q,b), 256 thr = 4 waves, no LDS.
// (unchanged from R4 — verified)
// ---------------------------------------------------------------------------
__global__ __launch_bounds__(256) void geo_mfma_kernel(
    const float* __restrict__ box, const int* __restrict__ mask,
    const float* __restrict__ WGw, const float* __restrict__ WGb,
    __half* __restrict__ LB)
{
    const int q = blockIdx.x;
    const int b = blockIdx.y;
    const int t = threadIdx.x;
    const int w = t >> 6, lane = t & 63;
    const int n = lane & 15;
    const int quad = lane >> 4;

    const float4 bq_ = *(const float4*)(box + (b * Nv + q) * 4);
    const float cxq = (bq_.x + bq_.z) * 0.5f;
    const float cyq = (bq_.y + bq_.w) * 0.5f;
    const float wq  = bq_.z - bq_.x + 1.0f;
    const float hq  = bq_.w - bq_.y + 1.0f;

    fp16x8 Bh0 = {}, Bl0 = {}, Bh1 = {}, Bl1 = {};
    float bias_n = 0.0f;
    if (n < Hv) {
        bias_n = WGb[n];
#pragma unroll
        for (int j = 0; j < 8; ++j) {
            const float w0 = WGw[n * 64 + quad * 8 + j];
            const float w1 = WGw[n * 64 + 32 + quad * 8 + j];
            const __fp16 h0 = (__fp16)w0;
            const __fp16 h1 = (__fp16)w1;
            Bh0[j] = h0; Bl0[j] = (__fp16)(w0 - (float)h0);
            Bh1[j] = h1; Bl1[j] = (__fp16)(w1 - (float)h1);
        }
    }

    const float dimm[8] = {1.0f, 0.42169650342f, 0.17782794100f, 0.07498942093f,
                           0.03162277660f, 0.01333521432f, 0.00562341325f, 0.00237137371f};
    const bool isCtr = (quad < 2);
    const bool isY   = (quad & 1);
    const float cq  = isY ? cyq : cxq;
    const float sq_ = isY ? hq : wq;

    for (int i = 0; i < 4; ++i) {
        const int m0 = (w * 4 + i) * 16;
        const float4 bm = *(const float4*)(box + (b * Nv + m0 + n) * 4);
        const float cxm = (bm.x + bm.z) * 0.5f;
        const float cym = (bm.y + bm.w) * 0.5f;
        const float wm  = bm.z - bm.x + 1.0f;
        const float hm  = bm.w - bm.y + 1.0f;
        const float cm_ = isY ? cym : cxm;
        const float sm_ = isY ? hm : wm;
        const float top = isCtr ? fabsf(cq - cm_) : sq_;
        const float bot = isCtr ? sq_ : sm_;
        float r = top / bot;
        if (isCtr) r = fmaxf(r, 1e-3f);
        const float base = 100.0f * __logf(r);

        fp16x8 Ash, Asl, Ach, Acl;
#pragma unroll
        for (int j = 0; j < 8; ++j) {
            float s, c;
            __sincosf(base * dimm[j], &s, &c);
            const __fp16 hs = (__fp16)s;
            const __fp16 hc = (__fp16)c;
            Ash[j] = hs; Asl[j] = (__fp16)(s - (float)hs);
            Ach[j] = hc; Acl[j] = (__fp16)(c - (float)hc);
        }

        f32x4 acc = {};
        acc = __builtin_amdgcn_mfma_f32_16x16x32_f16(Ash, Bh0, acc, 0, 0, 0);
        acc = __builtin_amdgcn_mfma_f32_16x16x32_f16(Asl, Bh0, acc, 0, 0, 0);
        acc = __builtin_amdgcn_mfma_f32_16x16x32_f16(Ash, Bl0, acc, 0, 0, 0);
        acc = __builtin_amdgcn_mfma_f32_16x16x32_f16(Ach, Bh1, acc, 0, 0, 0);
        acc = __builtin_amdgcn_mfma_f32_16x16x32_f16(Acl, Bh1, acc, 0, 0, 0);
        acc = __builtin_amdgcn_mfma_f32_16x16x32_f16(Ach, Bl1, acc, 0, 0, 0);

        const int mrow = m0 + quad * 4;
        const int4 mk = *(const int4*)(mask + b * Nv + mrow);
        if (n < Hv) {
            const int* mkp = (const int*)&mk;
            ushort4 o;
            unsigned short os[4];
#pragma unroll
            for (int rr = 0; rr < 4; ++rr) {
                const float val = fmaxf(acc[rr] + bias_n, 1e-6f);
                const float lb = __logf(val) + (mkp[rr] ? 0.0f : -30000.0f);
                os[rr] = __half_as_ushort(__float2half(lb));
            }
            o.x = os[0]; o.y = os[1]; o.z = os[2]; o.w = os[3];
            *(ushort4*)((unsigned short*)LB +
                        ((size_t)(b * Hv + n) * Nv + q) * Nv + mrow) = o;
        }
    }
}

// ---------------------------------------------------------------------------
// attn3 (MFMA): block=(64q, h, b), 4 waves; wave owns 16 q rows.
// QK^T: LB preloaded as MFMA C accumulator; Q pre-scaled 1/8 at projection.
// Softmax fully in registers (row = one 16-lane quad, 4 shfl_xor).
// P (bf16) -> LDS aliasing dead K buffer (wave-private rows -> no 3rd barrier).
// PV vs V^T (written transposed by the V-projection GEMM).
// LDS: Qs 9.2K + Ks/Pb 36.9K + Vt 33.8K = 78K -> 2 blocks/CU.
// ---------------------------------------------------------------------------
__global__ __launch_bounds__(256) void attn3_kernel(
    const unsigned short* __restrict__ Qb2, const unsigned short* __restrict__ Kb2,
    const unsigned short* __restrict__ Vt2, const __half* __restrict__ LB,
    unsigned short* __restrict__ CTXb)
{
    const int qt = blockIdx.x, h = blockIdx.y, b = blockIdx.z;
    const int q0 = qt * 64;
    const int t = threadIdx.x, w = t >> 6, lane = t & 63;
    const int fr = lane & 15, fq = lane >> 4;

    __shared__ unsigned short Qs[64][72];
    __shared__ unsigned short Ks[256][72];
    __shared__ unsigned short Vt[64][264];
    unsigned short (*Pb)[264] = (unsigned short (*)[264])&Ks[0][0];

    // ---- stage bf16 global -> padded LDS (16B units) ----
#pragma unroll
    for (int i = 0; i < 2; ++i) {          // Q: 512 units
        const int idx = t + i * 256;
        const int row = idx >> 3, cu = idx & 7;
        *(bf16x8*)&Qs[row][cu * 8] =
            *(const bf16x8*)(Qb2 + (size_t)(b * Nv + q0 + row) * Dv + h * 64 + cu * 8);
    }
#pragma unroll
    for (int i = 0; i < 8; ++i) {          // K: 2048 units
        const int idx = t + i * 256;
        const int row = idx >> 3, cu = idx & 7;
        *(bf16x8*)&Ks[row][cu * 8] =
            *(const bf16x8*)(Kb2 + (size_t)(b * Nv + row) * Dv + h * 64 + cu * 8);
    }
#pragma unroll
    for (int i = 0; i < 8; ++i) {          // V^T: 2048 units
        const int idx = t + i * 256;
        const int row = idx >> 5, cu = idx & 31;
        *(bf16x8*)&Vt[row][cu * 8] =
            *(const bf16x8*)(Vt2 + (size_t)b * (Dv * Nv) + (h * 64 + row) * Nv + cu * 8);
    }

    // ---- acc init from LB (C/D layout: row=fq*4+r, col=nt*16+fr) ----
    f32x4 acc[16];
    const int qb = q0 + w * 16 + fq * 4;
    const __half* lbp = LB + ((size_t)(b * Hv + h) * Nv + qb) * Nv + fr;
#pragma unroll
    for (int nt = 0; nt < 16; ++nt)
#pragma unroll
        for (int r = 0; r < 4; ++r)
            acc[nt][r] = __half2float(lbp[(size_t)r * Nv + nt * 16]);

    __syncthreads();

    // ---- QK^T ----
    const bf16x8 aq0 = *(const bf16x8*)&Qs[w * 16 + fr][fq * 8];
    const bf16x8 aq1 = *(const bf16x8*)&Qs[w * 16 + fr][32 + fq * 8];
#pragma unroll
    for (int nt = 0; nt < 16; ++nt) {
        const bf16x8 bk0 = *(const bf16x8*)&Ks[nt * 16 + fr][fq * 8];
        const bf16x8 bk1 = *(const bf16x8*)&Ks[nt * 16 + fr][32 + fq * 8];
        acc[nt] = __builtin_amdgcn_mfma_f32_16x16x32_bf16(aq0, bk0, acc[nt], 0, 0, 0);
        acc[nt] = __builtin_amdgcn_mfma_f32_16x16x32_bf16(aq1, bk1, acc[nt], 0, 0, 0);
    }

    // ---- softmax in registers ----
    float ri[4];
#pragma unroll
    for (int r = 0; r < 4; ++r) {
        float mx = acc[0][r];
#pragma unroll
        for (int nt = 1; nt < 16; ++nt) mx = fmaxf(mx, acc[nt][r]);
        mx = fmaxf(mx, __shfl_xor(mx, 1));
        mx = fmaxf(mx, __shfl_xor(mx, 2));
        mx = fmaxf(mx, __shfl_xor(mx, 4));
        mx = fmaxf(mx, __shfl_xor(mx, 8));
        float s = 0.0f;
#pragma unroll
        for (int nt = 0; nt < 16; ++nt) {
            const float e = __expf(acc[nt][r] - mx);
            acc[nt][r] = e;
            s += e;
        }
        s += __shfl_xor(s, 1);
        s += __shfl_xor(s, 2);
        s += __shfl_xor(s, 4);
        s += __shfl_xor(s, 8);
        ri[r] = 1.0f / s;
    }

    __syncthreads();   // all Ks reads complete before P overwrites the buffer

    // ---- P -> LDS (bf16), wave-private rows ----
#pragma unroll
    for (int nt = 0; nt < 16; ++nt)
#pragma unroll
        for (int r = 0; r < 4; ++r)
            Pb[w * 16 + fq * 4 + r][nt * 16 + fr] = f2bf(acc[nt][r] * ri[r]);

    // ---- PV: O[16q][64d] = P[16][256] @ (V^T rows) ----
    f32x4 o[4] = {};
#pragma unroll
    for (int kt = 0; kt < 8; ++kt) {
        const bf16x8 ap = *(const bf16x8*)&Pb[w * 16 + fr][kt * 32 + fq * 8];
#pragma unroll
        for (int nt2 = 0; nt2 < 4; ++nt2) {
            const bf16x8 bv_ = *(const bf16x8*)&Vt[nt2 * 16 + fr][kt * 32 + fq * 8];
            o[nt2] = __builtin_amdgcn_mfma_f32_16x16x32_bf16(ap, bv_, o[nt2], 0, 0, 0);
        }
    }

    // ---- epilogue: CTX bf16, row-major [b][m][512] ----
#pragma unroll
    for (int nt2 = 0; nt2 < 4; ++nt2)
#pragma unroll
        for (int r = 0; r < 4; ++r)
            CTXb[(size_t)(b * Nv + qb + r) * Dv + h * 64 + nt2 * 16 + fr] =
                f2bf(o[nt2][r]);
}

// ---------------------------------------------------------------------------
extern "C" void kernel_launch(void* const* d_in, const int* in_sizes, int n_in,
                              void* d_out, int out_size, void* d_ws, size_t ws_size,
                              hipStream_t stream) {
    (void)in_sizes; (void)n_in; (void)out_size; (void)ws_size;

    const float* inq  = (const float*)d_in[0];
    const float* ink  = (const float*)d_in[1];
    const float* inv  = (const float*)d_in[2];
    const float* box  = (const float*)d_in[3];
    const int*   mask = (const int*)d_in[4];
    const float* Wq   = (const float*)d_in[5];
    const float* bq   = (const float*)d_in[6];
    const float* Wk   = (const float*)d_in[7];
    const float* bk   = (const float*)d_in[8];
    const float* Wv   = (const float*)d_in[9];
    const float* bv   = (const float*)d_in[10];
    const float* Wo   = (const float*)d_in[11];
    const float* bo   = (const float*)d_in[12];
    const float* WGw  = (const float*)d_in[13];
    const float* WGb  = (const float*)d_in[14];

    char* W = (char*)d_ws;
    const size_t MB = 1048576;
    unsigned short* Qb2  = (unsigned short*)(W + 0);        // 4 MB bf16 [b][m][512], pre-scaled 1/8
    unsigned short* Kb2  = (unsigned short*)(W + 4 * MB);   // 4 MB bf16 [b][m][512]
    unsigned short* Vt2  = (unsigned short*)(W + 8 * MB);   // 4 MB bf16 [b][d][m] (transposed)
    unsigned short* Wt   = (unsigned short*)(W + 12 * MB);  // 2 MB (4 transposed weights)
    float*          bst  = (float*)(W + 14 * MB);           // 8 KB bias stack
    unsigned short* CTXb = (unsigned short*)(W + 15 * MB);  // 4 MB
    unsigned short* Ab   = (unsigned short*)(W + 20 * MB);  // 12 MB (3 bf16 input planes)
    __half*         LB   = (__half*)(W + 20 * MB);          // 16.8 MB, aliases Ab (dead after QKV)

    float* out = (float*)d_out;

    conv_b16_kernel<<<dim3(2048, 1, 3), 256, 0, stream>>>(inq, ink, inv, Ab);
    conv_w_kernel<<<dim3(8, 8, 4), 256, 0, stream>>>(Wq, Wk, Wv, Wo, bq, bk, bv, bo, Wt, bst);

    mfma_gemm2<1><<<dim3(4, 32), 256, 0, stream>>>(Ab, Wt, bst, Qb2, 0.125f);
    mfma_gemm2<1><<<dim3(4, 32), 256, 0, stream>>>(Ab + 1 * (size_t)MNv * Dv, Wt + Dv * Dv,
                                                   bst + Dv, Kb2, 1.0f);
    mfma_gemm2<2><<<dim3(4, 32), 256, 0, stream>>>(Ab + 2 * (size_t)MNv * Dv, Wt + 2 * Dv * Dv,
                                                   bst + 2 * Dv, Vt2, 1.0f);

    geo_mfma_kernel<<<dim3(Nv, Bv), 256, 0, stream>>>(box, mask, WGw, WGb, LB);

    attn3_kernel<<<dim3(4, 8, 16), 256, 0, stream>>>(Qb2, Kb2, Vt2, LB, CTXb);

    mfma_gemm2<0><<<dim3(4, 32), 256, 0, stream>>>(CTXb, Wt + 3 * Dv * Dv, bst + 3 * Dv, out, 1.0f);
}

// Round 6
// 188.381 us; speedup vs baseline: 5.5420x; 1.0438x over previous
//
#include <hip/hip_runtime.h>
#include <hip/hip_fp16.h>
#include <math.h>

#define Bv   16
#define Nv   256
#define Dv   512
#define Hv   8
#define MNv  4096          // B*N tokens

typedef __attribute__((ext_vector_type(8))) short bf16x8;
typedef __attribute__((ext_vector_type(4))) float f32x4;
typedef __fp16 fp16x8 __attribute__((ext_vector_type(8)));

__device__ __forceinline__ unsigned short f2bf(float f) {   // RNE
    unsigned u = __float_as_uint(f);
    u = u + 0x7FFFu + ((u >> 16) & 1u);
    return (unsigned short)(u >> 16);
}
__device__ __forceinline__ void gload_lds16(const void* g, void* l) {
    __builtin_amdgcn_global_load_lds(
        (const __attribute__((address_space(1))) unsigned int*)g,
        (__attribute__((address_space(3))) unsigned int*)l, 16, 0, 0);
}

// ---------------------------------------------------------------------------
// fp32 -> bf16 for the 3 projection inputs (z selects).
// ---------------------------------------------------------------------------
__global__ __launch_bounds__(256) void conv_b16_kernel(
    const float* __restrict__ xq, const float* __restrict__ xk,
    const float* __restrict__ xv, unsigned short* __restrict__ Ab)
{
    const int z = blockIdx.z;
    const float* src = (z == 0) ? xq : (z == 1) ? xk : xv;
    const size_t base = (size_t)z * (MNv * Dv);
    const int idx = (blockIdx.x * 256 + threadIdx.x) * 4;
    float4 x = *(const float4*)(src + idx);
    ushort4 h;
    h.x = f2bf(x.x); h.y = f2bf(x.y); h.z = f2bf(x.z); h.w = f2bf(x.w);
    *(ushort4*)(Ab + base + idx) = h;
}

// ---------------------------------------------------------------------------
// W[k][n] fp32 -> Wt[n][k] bf16 (transposed), all 4 weights (z); also stacks
// the 4 biases into biasStack[z][512].
// ---------------------------------------------------------------------------
__global__ __launch_bounds__(256) void conv_w_kernel(
    const float* __restrict__ Wq, const float* __restrict__ Wk,
    const float* __restrict__ Wv, const float* __restrict__ Wo,
    const float* __restrict__ bq, const float* __restrict__ bk,
    const float* __restrict__ bv, const float* __restrict__ bo,
    unsigned short* __restrict__ Wt, float* __restrict__ biasStack)
{
    const int z = blockIdx.z;
    const float* W = (z == 0) ? Wq : (z == 1) ? Wk : (z == 2) ? Wv : Wo;
    const float* b = (z == 0) ? bq : (z == 1) ? bk : (z == 2) ? bv : bo;
    const int n0 = blockIdx.x * 64, k0 = blockIdx.y * 64;
    const int t = threadIdx.x;
    __shared__ float T[64][65];
    const int col = t & 63, rb = t >> 6;
#pragma unroll
    for (int i = 0; i < 16; ++i) {
        const int row = i * 4 + rb;
        T[row][col] = W[(k0 + row) * Dv + n0 + col];
    }
    __syncthreads();
#pragma unroll
    for (int i = 0; i < 16; ++i) {
        const int row = i * 4 + rb;
        Wt[z * (Dv * Dv) + (n0 + row) * Dv + k0 + col] = f2bf(T[col][row]);
    }
    if (blockIdx.x == 0 && blockIdx.y == 0) {
        biasStack[z * Dv + t]       = b[t];
        biasStack[z * Dv + t + 256] = b[t + 256];
    }
}

// ---------------------------------------------------------------------------
// Fused Q/K/V projection GEMM, one launch, grid (4,32,3) = 384 blocks.
// z=0: Q bf16 row-major scaled 1/8; z=1: K bf16 row-major;
// z=2: V bf16 transposed per-batch [b][d][m].
// 128x128 tile, 4 waves 2x2, BK=32, global_load_lds width 16.
// ---------------------------------------------------------------------------
__global__ __launch_bounds__(256) void qkv_gemm_kernel(
    const unsigned short* __restrict__ Ab, const unsigned short* __restrict__ Wt,
    const float* __restrict__ bst, unsigned short* __restrict__ Qb2,
    unsigned short* __restrict__ Kb2, unsigned short* __restrict__ Vt2)
{
    const int z = blockIdx.z;
    const unsigned short* A = Ab + (size_t)z * (MNv * Dv);
    const unsigned short* Wz = Wt + (size_t)z * (Dv * Dv);
    const float* bias = bst + z * Dv;

    const int n0 = blockIdx.x * 128;
    const int m0 = blockIdx.y * 128;
    const int t = threadIdx.x;
    const int w = t >> 6, lane = t & 63;
    const int wm = w & 1, wn = w >> 1;

    __shared__ unsigned short As[128][32];
    __shared__ unsigned short Bs[128][32];

    f32x4 acc[4][4] = {};

    const int sr = lane >> 2;
    const int sk = (lane & 3) * 8;
    const int fr = lane & 15;
    const int fk = (lane >> 4) * 8;

    for (int k0 = 0; k0 < Dv; k0 += 32) {
        __syncthreads();
#pragma unroll
        for (int j = 0; j < 2; ++j) {
            const int row = w * 32 + j * 16 + sr;
            gload_lds16(A  + (size_t)(m0 + row) * Dv + k0 + sk, &As[w * 32 + j * 16][0]);
            gload_lds16(Wz + (size_t)(n0 + row) * Dv + k0 + sk, &Bs[w * 32 + j * 16][0]);
        }
        __syncthreads();

        bf16x8 af[4], bfr[4];
#pragma unroll
        for (int mt = 0; mt < 4; ++mt)
            af[mt] = *(const bf16x8*)&As[wm * 64 + mt * 16 + fr][fk];
#pragma unroll
        for (int nt = 0; nt < 4; ++nt)
            bfr[nt] = *(const bf16x8*)&Bs[wn * 64 + nt * 16 + fr][fk];
#pragma unroll
        for (int mt = 0; mt < 4; ++mt)
#pragma unroll
            for (int nt = 0; nt < 4; ++nt)
                acc[mt][nt] = __builtin_amdgcn_mfma_f32_16x16x32_bf16(
                    af[mt], bfr[nt], acc[mt][nt], 0, 0, 0);
    }

    const int er = (lane >> 4) * 4;
    const int ec = lane & 15;
    const float scale = (z == 0) ? 0.125f : 1.0f;
#pragma unroll
    for (int nt = 0; nt < 4; ++nt) {
        const int gn = n0 + wn * 64 + nt * 16 + ec;
        const float bv_ = bias[gn];
#pragma unroll
        for (int mt = 0; mt < 4; ++mt) {
            const int gm = m0 + wm * 64 + mt * 16 + er;
            if (z == 2) {
                ushort4 o;
                o.x = f2bf(acc[mt][nt][0] + bv_);
                o.y = f2bf(acc[mt][nt][1] + bv_);
                o.z = f2bf(acc[mt][nt][2] + bv_);
                o.w = f2bf(acc[mt][nt][3] + bv_);
                *(ushort4*)(Vt2 + ((size_t)(gm >> 8) * Dv + gn) * Nv + (gm & 255)) = o;
            } else {
                unsigned short* cp = ((z == 0) ? Qb2 : Kb2) + (size_t)gm * Dv + gn;
#pragma unroll
                for (int r = 0; r < 4; ++r)
                    cp[(size_t)r * Dv] = f2bf((acc[mt][nt][r] + bv_) * scale);
            }
        }
    }
}

// ---------------------------------------------------------------------------
// Output GEMM: out[4096][512] = CTXb @ Wo^T + bias, fp32.  128x64 tile,
// grid (8,32) = 256 blocks (full GPU).  Waves 2x2: wave tile 64m x 32n.
// ---------------------------------------------------------------------------
__global__ __launch_bounds__(256) void out_gemm_kernel(
    const unsigned short* __restrict__ A, const unsigned short* __restrict__ Wz,
    const float* __restrict__ bias, float* __restrict__ C)
{
    const int n0 = blockIdx.x * 64;
    const int m0 = blockIdx.y * 128;
    const int t = threadIdx.x;
    const int w = t >> 6, lane = t & 63;
    const int wm = w & 1, wn = w >> 1;

    __shared__ unsigned short As[128][32];
    __shared__ unsigned short Bs[64][32];

    f32x4 acc[4][2] = {};

    const int sr = lane >> 2;
    const int sk = (lane & 3) * 8;
    const int fr = lane & 15;
    const int fk = (lane >> 4) * 8;

    for (int k0 = 0; k0 < Dv; k0 += 32) {
        __syncthreads();
#pragma unroll
        for (int j = 0; j < 2; ++j) {
            const int row = w * 32 + j * 16 + sr;
            gload_lds16(A + (size_t)(m0 + row) * Dv + k0 + sk, &As[w * 32 + j * 16][0]);
        }
        gload_lds16(Wz + (size_t)(n0 + w * 16 + sr) * Dv + k0 + sk, &Bs[w * 16][0]);
        __syncthreads();

        bf16x8 af[4], bfr[2];
#pragma unroll
        for (int mt = 0; mt < 4; ++mt)
            af[mt] = *(const bf16x8*)&As[wm * 64 + mt * 16 + fr][fk];
#pragma unroll
        for (int nt = 0; nt < 2; ++nt)
            bfr[nt] = *(const bf16x8*)&Bs[wn * 32 + nt * 16 + fr][fk];
#pragma unroll
        for (int mt = 0; mt < 4; ++mt)
#pragma unroll
            for (int nt = 0; nt < 2; ++nt)
                acc[mt][nt] = __builtin_amdgcn_mfma_f32_16x16x32_bf16(
                    af[mt], bfr[nt], acc[mt][nt], 0, 0, 0);
    }

    const int er = (lane >> 4) * 4;
    const int ec = lane & 15;
#pragma unroll
    for (int nt = 0; nt < 2; ++nt) {
        const int gn = n0 + wn * 32 + nt * 16 + ec;
        const float bv_ = bias[gn];
#pragma unroll
        for (int mt = 0; mt < 4; ++mt) {
            const int gm = m0 + wm * 64 + mt * 16 + er;
            float* cp = C + (size_t)gm * Dv + gn;
#pragma unroll
            for (int r = 0; r < 4; ++r)
                cp[(size_t)r * Dv] = acc[mt][nt][r] + bv_;
        }
    }
}

// ---------------------------------------------------------------------------
// Geometric log-bias via MFMA.  Block=(q,b), 256 thr = 4 waves, no LDS.
// LB layout permuted in m: LB[b][h][q][(m&15)*16 + (m>>4)] so attn3's
// C-fragment init reads contiguous 16-half runs.
// ---------------------------------------------------------------------------
__global__ __launch_bounds__(256) void geo_mfma_kernel(
    const float* __restrict__ box, const int* __restrict__ mask,
    const float* __restrict__ WGw, const float* __restrict__ WGb,
    __half* __restrict__ LB)
{
    const int q = blockIdx.x;
    const int b = blockIdx.y;
    const int t = threadIdx.x;
    const int w = t >> 6, lane = t & 63;
    const int n = lane & 15;
    const int quad = lane >> 4;

    const float4 bq_ = *(const float4*)(box + (b * Nv + q) * 4);
    const float cxq = (bq_.x + bq_.z) * 0.5f;
    const float cyq = (bq_.y + bq_.w) * 0.5f;
    const float wq  = bq_.z - bq_.x + 1.0f;
    const float hq  = bq_.w - bq_.y + 1.0f;

    fp16x8 Bh0 = {}, Bl0 = {}, Bh1 = {}, Bl1 = {};
    float bias_n = 0.0f;
    if (n < Hv) {
        bias_n = WGb[n];
#pragma unroll
        for (int j = 0; j < 8; ++j) {
            const float w0 = WGw[n * 64 + quad * 8 + j];
            const float w1 = WGw[n * 64 + 32 + quad * 8 + j];
            const __fp16 h0 = (__fp16)w0;
            const __fp16 h1 = (__fp16)w1;
            Bh0[j] = h0; Bl0[j] = (__fp16)(w0 - (float)h0);
            Bh1[j] = h1; Bl1[j] = (__fp16)(w1 - (float)h1);
        }
    }

    const float dimm[8] = {1.0f, 0.42169650342f, 0.17782794100f, 0.07498942093f,
                           0.03162277660f, 0.01333521432f, 0.00562341325f, 0.00237137371f};
    const bool isCtr = (quad < 2);
    const bool isY   = (quad & 1);
    const float cq  = isY ? cyq : cxq;
    const float sq_ = isY ? hq : wq;

    for (int i = 0; i < 4; ++i) {
        const int m0 = (w * 4 + i) * 16;
        const float4 bm = *(const float4*)(box + (b * Nv + m0 + n) * 4);
        const float cxm = (bm.x + bm.z) * 0.5f;
        const float cym = (bm.y + bm.w) * 0.5f;
        const float wm  = bm.z - bm.x + 1.0f;
        const float hm  = bm.w - bm.y + 1.0f;
        const float cm_ = isY ? cym : cxm;
        const float sm_ = isY ? hm : wm;
        const float top = isCtr ? fabsf(cq - cm_) : sq_;
        const float bot = isCtr ? sq_ : sm_;
        float r = top / bot;
        if (isCtr) r = fmaxf(r, 1e-3f);
        const float base = 100.0f * __logf(r);

        fp16x8 Ash, Asl, Ach, Acl;
#pragma unroll
        for (int j = 0; j < 8; ++j) {
            float s, c;
            __sincosf(base * dimm[j], &s, &c);
            const __fp16 hs = (__fp16)s;
            const __fp16 hc = (__fp16)c;
            Ash[j] = hs; Asl[j] = (__fp16)(s - (float)hs);
            Ach[j] = hc; Acl[j] = (__fp16)(c - (float)hc);
        }

        f32x4 acc = {};
        acc = __builtin_amdgcn_mfma_f32_16x16x32_f16(Ash, Bh0, acc, 0, 0, 0);
        acc = __builtin_amdgcn_mfma_f32_16x16x32_f16(Asl, Bh0, acc, 0, 0, 0);
        acc = __builtin_amdgcn_mfma_f32_16x16x32_f16(Ash, Bl0, acc, 0, 0, 0);
        acc = __builtin_amdgcn_mfma_f32_16x16x32_f16(Ach, Bh1, acc, 0, 0, 0);
        acc = __builtin_amdgcn_mfma_f32_16x16x32_f16(Acl, Bh1, acc, 0, 0, 0);
        acc = __builtin_amdgcn_mfma_f32_16x16x32_f16(Ach, Bl1, acc, 0, 0, 0);

        // epilogue: key m = m0 + quad*4 + rr, head n; permuted pos in m.
        const int mrow = m0 + quad * 4;
        const int4 mk = *(const int4*)(mask + b * Nv + mrow);
        if (n < Hv) {
            const int* mkp = (const int*)&mk;
            unsigned short* dst = (unsigned short*)LB +
                                  ((size_t)(b * Hv + n) * Nv + q) * Nv;
            const int pos0 = (quad * 4) * 16 + (w * 4 + i);
#pragma unroll
            for (int rr = 0; rr < 4; ++rr) {
                const float val = fmaxf(acc[rr] + bias_n, 1e-6f);
                const float lb = __logf(val) + (mkp[rr] ? 0.0f : -30000.0f);
                dst[pos0 + rr * 16] = __half_as_ushort(__float2half(lb));
            }
        }
    }
}

// ---------------------------------------------------------------------------
// attn3 (MFMA): block=(64q, h, b), 4 waves; wave owns 16 q rows.
// LB (permuted) preloaded as MFMA C accumulator; Q pre-scaled 1/8.
// Softmax in registers; P -> LDS (aliasing dead K); PV vs V^T.
// LDS: Qs 9.2K + Ks/Pb 36.9K + Vt 33.8K = 78K -> 2 blocks/CU.
// ---------------------------------------------------------------------------
__global__ __launch_bounds__(256) void attn3_kernel(
    const unsigned short* __restrict__ Qb2, const unsigned short* __restrict__ Kb2,
    const unsigned short* __restrict__ Vt2, const __half* __restrict__ LB,
    unsigned short* __restrict__ CTXb)
{
    const int qt = blockIdx.x, h = blockIdx.y, b = blockIdx.z;
    const int q0 = qt * 64;
    const int t = threadIdx.x, w = t >> 6, lane = t & 63;
    const int fr = lane & 15, fq = lane >> 4;

    __shared__ unsigned short Qs[64][72];
    __shared__ unsigned short Ks[256][72];
    __shared__ unsigned short Vt[64][264];
    unsigned short (*Pb)[264] = (unsigned short (*)[264])&Ks[0][0];

#pragma unroll
    for (int i = 0; i < 2; ++i) {          // Q
        const int idx = t + i * 256;
        const int row = idx >> 3, cu = idx & 7;
        *(bf16x8*)&Qs[row][cu * 8] =
            *(const bf16x8*)(Qb2 + (size_t)(b * Nv + q0 + row) * Dv + h * 64 + cu * 8);
    }
#pragma unroll
    for (int i = 0; i < 8; ++i) {          // K
        const int idx = t + i * 256;
        const int row = idx >> 3, cu = idx & 7;
        *(bf16x8*)&Ks[row][cu * 8] =
            *(const bf16x8*)(Kb2 + (size_t)(b * Nv + row) * Dv + h * 64 + cu * 8);
    }
#pragma unroll
    for (int i = 0; i < 8; ++i) {          // V^T
        const int idx = t + i * 256;
        const int row = idx >> 5, cu = idx & 31;
        *(bf16x8*)&Vt[row][cu * 8] =
            *(const bf16x8*)(Vt2 + (size_t)b * (Dv * Nv) + (h * 64 + row) * Nv + cu * 8);
    }

    // ---- acc init from permuted LB: row q=qb+r, 16 contiguous halfs @ fr*16
    f32x4 acc[16];
    const int qb = q0 + w * 16 + fq * 4;
    const __half* lbp = LB + ((size_t)(b * Hv + h) * Nv + qb) * Nv + fr * 16;
#pragma unroll
    for (int r = 0; r < 4; ++r) {
        union { int4 v; __half hs[8]; } u0, u1;
        const int4* p = (const int4*)(lbp + (size_t)r * Nv);
        u0.v = p[0]; u1.v = p[1];
#pragma unroll
        for (int nt = 0; nt < 8; ++nt) acc[nt][r]     = __half2float(u0.hs[nt]);
#pragma unroll
        for (int nt = 0; nt < 8; ++nt) acc[nt + 8][r] = __half2float(u1.hs[nt]);
    }

    __syncthreads();

    // ---- QK^T ----
    const bf16x8 aq0 = *(const bf16x8*)&Qs[w * 16 + fr][fq * 8];
    const bf16x8 aq1 = *(const bf16x8*)&Qs[w * 16 + fr][32 + fq * 8];
#pragma unroll
    for (int nt = 0; nt < 16; ++nt) {
        const bf16x8 bk0 = *(const bf16x8*)&Ks[nt * 16 + fr][fq * 8];
        const bf16x8 bk1 = *(const bf16x8*)&Ks[nt * 16 + fr][32 + fq * 8];
        acc[nt] = __builtin_amdgcn_mfma_f32_16x16x32_bf16(aq0, bk0, acc[nt], 0, 0, 0);
        acc[nt] = __builtin_amdgcn_mfma_f32_16x16x32_bf16(aq1, bk1, acc[nt], 0, 0, 0);
    }

    // ---- softmax in registers ----
    float ri[4];
#pragma unroll
    for (int r = 0; r < 4; ++r) {
        float mx = acc[0][r];
#pragma unroll
        for (int nt = 1; nt < 16; ++nt) mx = fmaxf(mx, acc[nt][r]);
        mx = fmaxf(mx, __shfl_xor(mx, 1));
        mx = fmaxf(mx, __shfl_xor(mx, 2));
        mx = fmaxf(mx, __shfl_xor(mx, 4));
        mx = fmaxf(mx, __shfl_xor(mx, 8));
        float s = 0.0f;
#pragma unroll
        for (int nt = 0; nt < 16; ++nt) {
            const float e = __expf(acc[nt][r] - mx);
            acc[nt][r] = e;
            s += e;
        }
        s += __shfl_xor(s, 1);
        s += __shfl_xor(s, 2);
        s += __shfl_xor(s, 4);
        s += __shfl_xor(s, 8);
        ri[r] = 1.0f / s;
    }

    __syncthreads();   // all Ks reads complete before P overwrites the buffer

#pragma unroll
    for (int nt = 0; nt < 16; ++nt)
#pragma unroll
        for (int r = 0; r < 4; ++r)
            Pb[w * 16 + fq * 4 + r][nt * 16 + fr] = f2bf(acc[nt][r] * ri[r]);

    // ---- PV ----
    f32x4 o[4] = {};
#pragma unroll
    for (int kt = 0; kt < 8; ++kt) {
        const bf16x8 ap = *(const bf16x8*)&Pb[w * 16 + fr][kt * 32 + fq * 8];
#pragma unroll
        for (int nt2 = 0; nt2 < 4; ++nt2) {
            const bf16x8 bv_ = *(const bf16x8*)&Vt[nt2 * 16 + fr][kt * 32 + fq * 8];
            o[nt2] = __builtin_amdgcn_mfma_f32_16x16x32_bf16(ap, bv_, o[nt2], 0, 0, 0);
        }
    }

#pragma unroll
    for (int nt2 = 0; nt2 < 4; ++nt2)
#pragma unroll
        for (int r = 0; r < 4; ++r)
            CTXb[(size_t)(b * Nv + qb + r) * Dv + h * 64 + nt2 * 16 + fr] =
                f2bf(o[nt2][r]);
}

// ---------------------------------------------------------------------------
extern "C" void kernel_launch(void* const* d_in, const int* in_sizes, int n_in,
                              void* d_out, int out_size, void* d_ws, size_t ws_size,
                              hipStream_t stream) {
    (void)in_sizes; (void)n_in; (void)out_size; (void)ws_size;

    const float* inq  = (const float*)d_in[0];
    const float* ink  = (const float*)d_in[1];
    const float* inv  = (const float*)d_in[2];
    const float* box  = (const float*)d_in[3];
    const int*   mask = (const int*)d_in[4];
    const float* Wq   = (const float*)d_in[5];
    const float* bq   = (const float*)d_in[6];
    const float* Wk   = (const float*)d_in[7];
    const float* bk   = (const float*)d_in[8];
    const float* Wv   = (const float*)d_in[9];
    const float* bv   = (const float*)d_in[10];
    const float* Wo   = (const float*)d_in[11];
    const float* bo   = (const float*)d_in[12];
    const float* WGw  = (const float*)d_in[13];
    const float* WGb  = (const float*)d_in[14];

    char* W = (char*)d_ws;
    const size_t MB = 1048576;
    unsigned short* Qb2  = (unsigned short*)(W + 0);        // 4 MB bf16 [b][m][512], pre-scaled 1/8
    unsigned short* Kb2  = (unsigned short*)(W + 4 * MB);   // 4 MB bf16 [b][m][512]
    unsigned short* Vt2  = (unsigned short*)(W + 8 * MB);   // 4 MB bf16 [b][d][m]
    unsigned short* Wt   = (unsigned short*)(W + 12 * MB);  // 2 MB (4 transposed weights)
    float*          bst  = (float*)(W + 14 * MB);           // 8 KB bias stack
    unsigned short* CTXb = (unsigned short*)(W + 15 * MB);  // 4 MB
    unsigned short* Ab   = (unsigned short*)(W + 20 * MB);  // 12 MB (3 bf16 input planes)
    __half*         LB   = (__half*)(W + 20 * MB);          // 16.8 MB, aliases Ab (dead after QKV)

    float* out = (float*)d_out;

    conv_b16_kernel<<<dim3(2048, 1, 3), 256, 0, stream>>>(inq, ink, inv, Ab);
    conv_w_kernel<<<dim3(8, 8, 4), 256, 0, stream>>>(Wq, Wk, Wv, Wo, bq, bk, bv, bo, Wt, bst);

    qkv_gemm_kernel<<<dim3(4, 32, 3), 256, 0, stream>>>(Ab, Wt, bst, Qb2, Kb2, Vt2);

    geo_mfma_kernel<<<dim3(Nv, Bv), 256, 0, stream>>>(box, mask, WGw, WGb, LB);

    attn3_kernel<<<dim3(4, 8, 16), 256, 0, stream>>>(Qb2, Kb2, Vt2, LB, CTXb);

    out_gemm_kernel<<<dim3(8, 32), 256, 0, stream>>>(CTXb, Wt + 3 * (Dv * Dv), bst + 3 * Dv, out);
}